// Round 1
// baseline (7995.473 us; speedup 1.0000x reference)
//
#include <hip/hip_runtime.h>
#include <math.h>

#define EE 768
#define NS 16
#define RR 48
#define NDEPTH 4
#define NB 2
#define NL 1024
#define NH 3072
#define NV 32000
#define M_ROWS (NB*NL)   // 2048

// ---------------- GEMM: C = A @ W^T (+bias, +activation, +residual) ----------------
// A: M x K row-major (lda), W: N x K row-major, C: M x ldc
enum { EPI_STORE=0, EPI_BIAS=1, EPI_BIAS_GELU=2, EPI_SOFTPLUS_BIAS=3, EPI_RESID=4, EPI_BIAS_RESID=5 };

template<int EPI>
__global__ __launch_bounds__(256) void gemm_wt(const float* __restrict__ A, int lda,
    const float* __restrict__ W, const float* __restrict__ bias,
    float* __restrict__ C, int ldc, int N, int K)
{
  __shared__ __align__(16) float As[16][68];
  __shared__ __align__(16) float Ws[16][68];
  const int bm = blockIdx.y*64, bn = blockIdx.x*64;
  const int t = threadIdx.x;
  const int lr = t>>2;          // 0..63
  const int lk = (t&3)<<2;      // 0,4,8,12
  const int ty = t>>4, tx = t&15;
  float acc[4][4] = {};
  for (int k0=0;k0<K;k0+=16){
    float4 av = *(const float4*)(A + (size_t)(bm+lr)*lda + k0 + lk);
    float4 wv = make_float4(0.f,0.f,0.f,0.f);
    if (bn+lr < N) wv = *(const float4*)(W + (size_t)(bn+lr)*K + k0 + lk);
    __syncthreads();
    As[lk+0][lr]=av.x; As[lk+1][lr]=av.y; As[lk+2][lr]=av.z; As[lk+3][lr]=av.w;
    Ws[lk+0][lr]=wv.x; Ws[lk+1][lr]=wv.y; Ws[lk+2][lr]=wv.z; Ws[lk+3][lr]=wv.w;
    __syncthreads();
    #pragma unroll
    for (int kk=0;kk<16;kk++){
      float4 a = *(const float4*)&As[kk][ty<<2];
      float4 b = *(const float4*)&Ws[kk][tx<<2];
      float ar[4] = {a.x,a.y,a.z,a.w};
      float br[4] = {b.x,b.y,b.z,b.w};
      #pragma unroll
      for (int i=0;i<4;i++)
        #pragma unroll
        for (int j=0;j<4;j++)
          acc[i][j] = fmaf(ar[i], br[j], acc[i][j]);
    }
  }
  #pragma unroll
  for (int i=0;i<4;i++){
    int row = bm + (ty<<2) + i;
    #pragma unroll
    for (int j=0;j<4;j++){
      int col = bn + (tx<<2) + j;
      if (col >= N) continue;
      float v = acc[i][j];
      size_t idx = (size_t)row*ldc + col;
      if (EPI==EPI_STORE) C[idx]=v;
      else if (EPI==EPI_BIAS) C[idx]=v+bias[col];
      else if (EPI==EPI_BIAS_GELU){ float xg=v+bias[col]; C[idx]=0.5f*xg*(1.f+erff(xg*0.70710678118654752f)); }
      else if (EPI==EPI_SOFTPLUS_BIAS){ float xg=v+bias[col]; C[idx]=fmaxf(xg,0.f)+log1pf(expf(-fabsf(xg))); }
      else if (EPI==EPI_RESID) C[idx]+=v;
      else if (EPI==EPI_BIAS_RESID) C[idx]+=v+bias[col];
    }
  }
}

// ---------------- LayerNorm (row = 768) ----------------
__global__ __launch_bounds__(256) void ln_kernel(const float* __restrict__ x,
    const float* __restrict__ gp, const float* __restrict__ bp, float* __restrict__ y)
{
  int row = blockIdx.x;
  const float* xr = x + (size_t)row*EE;
  int t = threadIdx.x;
  float v0 = xr[t], v1 = xr[t+256], v2 = xr[t+512];
  float s = v0+v1+v2;
  #pragma unroll
  for (int m=1;m<64;m<<=1) s += __shfl_xor(s, m, 64);
  __shared__ float red[4], red2[4];
  int wid = t>>6;
  if ((t&63)==0) red[wid]=s;
  __syncthreads();
  float mu = (red[0]+red[1]+red[2]+red[3]) * (1.f/768.f);
  float d0=v0-mu, d1=v1-mu, d2=v2-mu;
  float q = d0*d0+d1*d1+d2*d2;
  #pragma unroll
  for (int m=1;m<64;m<<=1) q += __shfl_xor(q, m, 64);
  if ((t&63)==0) red2[wid]=q;
  __syncthreads();
  float var = (red2[0]+red2[1]+red2[2]+red2[3]) * (1.f/768.f);
  float inv = 1.0f/sqrtf(var + 1e-5f);
  float* yr = y + (size_t)row*EE;
  yr[t]     = d0*inv*gp[t]     + bp[t];
  yr[t+256] = d1*inv*gp[t+256] + bp[t+256];
  yr[t+512] = d2*inv*gp[t+512] + bp[t+512];
}

// ---------------- sinusoidal emb + time MLP (tiny) ----------------
__global__ void sinemb_kernel(const int* __restrict__ timesteps, float* __restrict__ emb){
  int i = blockIdx.x*256+threadIdx.x;
  if (i >= NB*EE) return;
  int b = i/EE, e = i - b*EE;
  int half = EE/2;
  int j = (e<half)? e : e-half;
  float freq = expf(-logf(10000.f)*(float)j/(float)half);
  float arg = (float)timesteps[b]*freq;
  emb[i] = (e<half)? sinf(arg) : cosf(arg);
}

__global__ void time_mlp1(const float* __restrict__ emb, const float* __restrict__ w1,
                          const float* __restrict__ b1, float* __restrict__ thid){
  int i = blockIdx.x*256+threadIdx.x;
  if (i >= NB*NH) return;
  int b = i/NH, h = i - b*NH;
  const float* er = emb + b*EE;
  const float* wr = w1 + (size_t)h*EE;
  float s = 0.f;
  for (int e=0;e<EE;e++) s = fmaf(er[e], wr[e], s);
  s += b1[h];
  thid[i] = s/(1.f+expf(-s));
}

__global__ void time_mlp2(const float* __restrict__ thid, const float* __restrict__ w2,
                          const float* __restrict__ b2, float* __restrict__ temb){
  int i = blockIdx.x*256+threadIdx.x;
  if (i >= NB*EE) return;
  int b = i/EE, e = i - b*EE;
  const float* tr = thid + b*NH;
  const float* wr = w2 + (size_t)e*NH;
  float s = 0.f;
  for (int h=0;h<NH;h++) s = fmaf(tr[h], wr[h], s);
  temb[i] = s + b2[e];
}

// ---------------- embedding ----------------
__global__ void embed_kernel(const int* __restrict__ tokens, const float* __restrict__ tok_emb,
                             const float* __restrict__ temb, float* __restrict__ x){
  int idx = blockIdx.x*256+threadIdx.x;   // B*L*E
  int e = idx % EE; int bl = idx / EE; int b = bl / NL;
  int tok = tokens[bl];
  x[idx] = tok_emb[(size_t)tok*EE + e] + temb[b*EE + e];
}

// ---------------- depthwise causal conv (K=4) + SiLU ----------------
__global__ void conv_silu(const float* __restrict__ xn, const float* __restrict__ w, float* __restrict__ u){
  int idx = blockIdx.x*256+threadIdx.x;   // B*L*E
  int e = idx % EE; int bl = idx / EE; int l = bl % NL;
  float acc = 0.f;
  #pragma unroll
  for (int k=0;k<4;k++){
    int ls = l-3+k;
    if (ls >= 0) acc = fmaf(w[e*4+k], xn[(size_t)(bl-3+k)*EE + e], acc);
  }
  u[idx] = acc/(1.f+expf(-acc));
}

// ---------------- sequential SSM scan; writes gated g = (y) * silu(z) ----------------
__global__ __launch_bounds__(256) void ssm_scan(const float* __restrict__ dt, const float* __restrict__ u,
    const float* __restrict__ params, const float* __restrict__ z,
    const float* __restrict__ A_log, const float* __restrict__ Dp, float* __restrict__ g)
{
  int t = blockIdx.x*256 + threadIdx.x;
  int chain = t >> 4;         // b*E + e
  int n = t & 15;
  int b = chain / EE, e = chain - b*EE;
  float A = -expf(A_log[e*NS + n]);
  float Dv = Dp[e];
  float h = 0.f, pa = 0.f, pb = 0.f, pu = 0.f;
  for (int l=0;l<NL;l++){
    size_t idx = (size_t)(b*NL+l)*EE + e;
    float dtv = dt[idx];
    float uv  = u[idx];
    float at = expf(dtv*A);
    float bt = (fabsf(A)<1e-5f) ? dtv : (at-1.f)/(A+1e-10f);
    if (l==0) h = bt*uv;
    else      h = fmaf(pa, h, pb*pu);
    float c = params[(size_t)(b*NL+l)*80 + 64 + n];
    float v = c*h;
    #pragma unroll
    for (int m=1;m<16;m<<=1) v += __shfl_xor(v, m, 16);
    if (n==0){
      float zv = z[idx];
      float sz = zv/(1.f+expf(-zv));
      g[idx] = (v + uv*Dv)*sz;
    }
    pa = at; pb = bt; pu = uv;
  }
}

extern "C" void kernel_launch(void* const* d_in, const int* in_sizes, int n_in,
                              void* d_out, int out_size, void* d_ws, size_t ws_size,
                              hipStream_t stream) {
  const int*   tokens    = (const int*)d_in[0];
  const int*   timesteps = (const int*)d_in[1];
  const float* tok_emb   = (const float*)d_in[2];
  const float* time_w1   = (const float*)d_in[3];
  const float* time_b1   = (const float*)d_in[4];
  const float* time_w2   = (const float*)d_in[5];
  const float* time_b2   = (const float*)d_in[6];
  const float* ln1_g     = (const float*)d_in[7];
  const float* ln1_b     = (const float*)d_in[8];
  const float* z_w       = (const float*)d_in[9];
  const float* p_w       = (const float*)d_in[10];
  const float* conv_w    = (const float*)d_in[11];
  const float* dtp_w     = (const float*)d_in[12];
  const float* dtp_b     = (const float*)d_in[13];
  const float* A_log     = (const float*)d_in[14];
  const float* D_param   = (const float*)d_in[15];
  const float* out_w     = (const float*)d_in[16];
  const float* ln2_g     = (const float*)d_in[17];
  const float* ln2_b     = (const float*)d_in[18];
  const float* mlp_w1    = (const float*)d_in[19];
  const float* mlp_b1    = (const float*)d_in[20];
  const float* mlp_w2    = (const float*)d_in[21];
  const float* mlp_b2    = (const float*)d_in[22];
  const float* lnout_g   = (const float*)d_in[23];
  const float* lnout_b   = (const float*)d_in[24];
  const float* head_w    = (const float*)d_in[25];
  const float* head_b    = (const float*)d_in[26];
  float* out = (float*)d_out;

  float* ws = (float*)d_ws;
  float* x      = ws;
  float* xn     = x   + (size_t)M_ROWS*EE;
  float* z      = xn  + (size_t)M_ROWS*EE;
  float* dt     = z   + (size_t)M_ROWS*EE;
  float* u      = dt  + (size_t)M_ROWS*EE;
  float* g      = u   + (size_t)M_ROWS*EE;
  float* params = g   + (size_t)M_ROWS*EE;
  float* hid    = params + (size_t)M_ROWS*80;
  float* emb    = hid + (size_t)M_ROWS*NH;
  float* thid   = emb + NB*EE;

  sinemb_kernel<<<(NB*EE+255)/256, 256, 0, stream>>>(timesteps, emb);
  time_mlp1<<<(NB*NH+255)/256, 256, 0, stream>>>(emb, time_w1, time_b1, thid);
  time_mlp2<<<(NB*EE+255)/256, 256, 0, stream>>>(thid, time_w2, time_b2, emb); // emb now holds temb
  embed_kernel<<<M_ROWS*EE/256, 256, 0, stream>>>(tokens, tok_emb, emb, x);

  for (int i=0;i<NDEPTH;i++){
    ln_kernel<<<M_ROWS, 256, 0, stream>>>(x, ln1_g + i*EE, ln1_b + i*EE, xn);
    gemm_wt<EPI_STORE><<<dim3(EE/64, M_ROWS/64), 256, 0, stream>>>(
        xn, EE, z_w + (size_t)i*EE*EE, nullptr, z, EE, EE, EE);
    gemm_wt<EPI_STORE><<<dim3(2, M_ROWS/64), 256, 0, stream>>>(
        xn, EE, p_w + (size_t)i*80*EE, nullptr, params, 80, 80, EE);
    gemm_wt<EPI_SOFTPLUS_BIAS><<<dim3(EE/64, M_ROWS/64), 256, 0, stream>>>(
        params, 80, dtp_w + (size_t)i*EE*RR, dtp_b + i*EE, dt, EE, EE, RR);
    conv_silu<<<M_ROWS*EE/256, 256, 0, stream>>>(xn, conv_w + (size_t)i*EE*4, u);
    ssm_scan<<<NB*EE*16/256, 256, 0, stream>>>(
        dt, u, params, z, A_log + (size_t)i*EE*NS, D_param + i*EE, g);
    gemm_wt<EPI_RESID><<<dim3(EE/64, M_ROWS/64), 256, 0, stream>>>(
        g, EE, out_w + (size_t)i*EE*EE, nullptr, x, EE, EE, EE);
    ln_kernel<<<M_ROWS, 256, 0, stream>>>(x, ln2_g + i*EE, ln2_b + i*EE, xn);
    gemm_wt<EPI_BIAS_GELU><<<dim3(NH/64, M_ROWS/64), 256, 0, stream>>>(
        xn, EE, mlp_w1 + (size_t)i*NH*EE, mlp_b1 + i*NH, hid, NH, NH, EE);
    gemm_wt<EPI_BIAS_RESID><<<dim3(EE/64, M_ROWS/64), 256, 0, stream>>>(
        hid, NH, mlp_w2 + (size_t)i*EE*NH, mlp_b2 + i*EE, x, EE, EE, NH);
  }
  ln_kernel<<<M_ROWS, 256, 0, stream>>>(x, lnout_g, lnout_b, xn);
  gemm_wt<EPI_BIAS><<<dim3(NV/64, M_ROWS/64), 256, 0, stream>>>(
      xn, EE, head_w, head_b, out, NV, NV, EE);
}

// Round 2
// 1845.160 us; speedup vs baseline: 4.3332x; 4.3332x over previous
//
#include <hip/hip_runtime.h>
#include <math.h>

#define EE 768
#define NS 16
#define RR 48
#define NDEPTH 4
#define NB 2
#define NL 1024
#define NH 3072
#define NV 32000
#define M_ROWS (NB*NL)   // 2048
#define NC 16            // scan chunks
#define CL 64            // chunk length

typedef __attribute__((ext_vector_type(8))) __bf16 bf16x8;
typedef __attribute__((ext_vector_type(4))) __bf16 bf16x4;
typedef __attribute__((ext_vector_type(4))) float f32x4;

__device__ __forceinline__ void gl_lds16(const __bf16* g, __bf16* l){
  __builtin_amdgcn_global_load_lds(
      (const __attribute__((address_space(1))) void*)g,
      (__attribute__((address_space(3))) void*)l, 16, 0, 0);
}

// ---------------- bf16 MFMA GEMM: C = A @ W^T (+epilogues) ----------------
// A: M x K bf16 row-major, W: N x K bf16 row-major. M,N multiples of 128, K multiple of 32.
enum { BE_STORE=0, BE_BIAS=1, BE_RESID=2, BE_BIAS_RESID=3, BE_BIAS_GELU_B16=4 };

template<int EPI>
__global__ __launch_bounds__(256) void gemm_bf16(const __bf16* __restrict__ A,
    const __bf16* __restrict__ W, const float* __restrict__ bias,
    void* __restrict__ Cv, int N, int K)
{
  __shared__ __bf16 As[128][32];
  __shared__ __bf16 Ws[128][32];
  const int bm = blockIdx.y*128, bn = blockIdx.x*128;
  const int tid = threadIdx.x;
  const int w = tid>>6, lane = tid&63;
  const int wr = w>>1, wc = w&1;
  const int fr = lane&15, kg = lane>>4;
  const int srow = lane>>2, sgran = lane&3;

  f32x4 acc[4][4];
  #pragma unroll
  for (int m=0;m<4;m++)
    #pragma unroll
    for (int n=0;n<4;n++)
      acc[m][n] = (f32x4){0.f,0.f,0.f,0.f};

  for (int k0=0;k0<K;k0+=32){
    const __bf16* gA = A + (size_t)(bm + w*32 + srow)*K + k0 + sgran*8;
    const __bf16* gW = W + (size_t)(bn + w*32 + srow)*K + k0 + sgran*8;
    gl_lds16(gA,                 &As[w*32][0]);
    gl_lds16(gA + (size_t)16*K,  &As[w*32+16][0]);
    gl_lds16(gW,                 &Ws[w*32][0]);
    gl_lds16(gW + (size_t)16*K,  &Ws[w*32+16][0]);
    __syncthreads();
    bf16x8 af[4], bfr[4];
    #pragma unroll
    for (int m=0;m<4;m++) af[m]  = *(const bf16x8*)&As[wr*64 + m*16 + fr][kg*8];
    #pragma unroll
    for (int n=0;n<4;n++) bfr[n] = *(const bf16x8*)&Ws[wc*64 + n*16 + fr][kg*8];
    #pragma unroll
    for (int m=0;m<4;m++)
      #pragma unroll
      for (int n=0;n<4;n++)
        acc[m][n] = __builtin_amdgcn_mfma_f32_16x16x32_bf16(af[m], bfr[n], acc[m][n], 0,0,0);
    __syncthreads();
  }

  float* Cf = (float*)Cv;
  __bf16* Cb = (__bf16*)Cv;
  #pragma unroll
  for (int m=0;m<4;m++){
    int row = bm + wr*64 + m*16 + kg*4;
    #pragma unroll
    for (int n=0;n<4;n++){
      int col = bn + wc*64 + n*16 + fr;
      float bsv = 0.f;
      if (EPI==BE_BIAS || EPI==BE_BIAS_RESID || EPI==BE_BIAS_GELU_B16) bsv = bias[col];
      #pragma unroll
      for (int r=0;r<4;r++){
        float v = acc[m][n][r];
        size_t idx = (size_t)(row+r)*N + col;
        if (EPI==BE_STORE)            Cf[idx] = v;
        else if (EPI==BE_BIAS)        Cf[idx] = v + bsv;
        else if (EPI==BE_RESID)       Cf[idx] += v;
        else if (EPI==BE_BIAS_RESID)  Cf[idx] += v + bsv;
        else { float xg = v + bsv; Cb[idx] = (__bf16)(0.5f*xg*(1.f+erff(xg*0.70710678118654752f))); }
      }
    }
  }
}

// ---------------- fp32→bf16 convert ----------------
__global__ void conv_f2b(const float* __restrict__ w, __bf16* __restrict__ o, int nelem){
  int i = (blockIdx.x*256 + threadIdx.x)*4;
  if (i >= nelem) return;
  float4 v = *(const float4*)(w+i);
  bf16x4 r = { (__bf16)v.x, (__bf16)v.y, (__bf16)v.z, (__bf16)v.w };
  *(bf16x4*)(o+i) = r;
}

// ---------------- fp32 GEMM (small: p_w N=80, dtp K=48) ----------------
enum { EPI_STORE=0, EPI_SOFTPLUS_BIAS=3 };

template<int EPI>
__global__ __launch_bounds__(256) void gemm_wt(const float* __restrict__ A, int lda,
    const float* __restrict__ W, const float* __restrict__ bias,
    float* __restrict__ C, int ldc, int N, int K)
{
  __shared__ __align__(16) float Asf[16][68];
  __shared__ __align__(16) float Wsf[16][68];
  const int bm = blockIdx.y*64, bn = blockIdx.x*64;
  const int t = threadIdx.x;
  const int lr = t>>2;
  const int lk = (t&3)<<2;
  const int ty = t>>4, tx = t&15;
  float acc[4][4] = {};
  for (int k0=0;k0<K;k0+=16){
    float4 av = *(const float4*)(A + (size_t)(bm+lr)*lda + k0 + lk);
    float4 wv = make_float4(0.f,0.f,0.f,0.f);
    if (bn+lr < N) wv = *(const float4*)(W + (size_t)(bn+lr)*K + k0 + lk);
    __syncthreads();
    Asf[lk+0][lr]=av.x; Asf[lk+1][lr]=av.y; Asf[lk+2][lr]=av.z; Asf[lk+3][lr]=av.w;
    Wsf[lk+0][lr]=wv.x; Wsf[lk+1][lr]=wv.y; Wsf[lk+2][lr]=wv.z; Wsf[lk+3][lr]=wv.w;
    __syncthreads();
    #pragma unroll
    for (int kk=0;kk<16;kk++){
      float4 a = *(const float4*)&Asf[kk][ty<<2];
      float4 b = *(const float4*)&Wsf[kk][tx<<2];
      float ar[4] = {a.x,a.y,a.z,a.w};
      float br[4] = {b.x,b.y,b.z,b.w};
      #pragma unroll
      for (int i=0;i<4;i++)
        #pragma unroll
        for (int j=0;j<4;j++)
          acc[i][j] = fmaf(ar[i], br[j], acc[i][j]);
    }
  }
  #pragma unroll
  for (int i=0;i<4;i++){
    int row = bm + (ty<<2) + i;
    #pragma unroll
    for (int j=0;j<4;j++){
      int col = bn + (tx<<2) + j;
      if (col >= N) continue;
      float v = acc[i][j];
      size_t idx = (size_t)row*ldc + col;
      if (EPI==EPI_STORE) C[idx]=v;
      else { float xg=v+bias[col]; C[idx]=fmaxf(xg,0.f)+log1pf(expf(-fabsf(xg))); }
    }
  }
}

// ---------------- LayerNorm (row = 768): fp32 out (nullable) + bf16 out ----------------
__global__ __launch_bounds__(256) void ln_kernel(const float* __restrict__ x,
    const float* __restrict__ gp, const float* __restrict__ bp,
    float* __restrict__ y, __bf16* __restrict__ yb)
{
  int row = blockIdx.x;
  const float* xr = x + (size_t)row*EE;
  int t = threadIdx.x;
  float v0 = xr[t], v1 = xr[t+256], v2 = xr[t+512];
  float s = v0+v1+v2;
  #pragma unroll
  for (int m=1;m<64;m<<=1) s += __shfl_xor(s, m, 64);
  __shared__ float red[4], red2[4];
  int wid = t>>6;
  if ((t&63)==0) red[wid]=s;
  __syncthreads();
  float mu = (red[0]+red[1]+red[2]+red[3]) * (1.f/768.f);
  float d0=v0-mu, d1=v1-mu, d2=v2-mu;
  float q = d0*d0+d1*d1+d2*d2;
  #pragma unroll
  for (int m=1;m<64;m<<=1) q += __shfl_xor(q, m, 64);
  if ((t&63)==0) red2[wid]=q;
  __syncthreads();
  float var = (red2[0]+red2[1]+red2[2]+red2[3]) * (1.f/768.f);
  float inv = 1.0f/sqrtf(var + 1e-5f);
  float o0 = d0*inv*gp[t]     + bp[t];
  float o1 = d1*inv*gp[t+256] + bp[t+256];
  float o2 = d2*inv*gp[t+512] + bp[t+512];
  if (y){
    float* yr = y + (size_t)row*EE;
    yr[t]=o0; yr[t+256]=o1; yr[t+512]=o2;
  }
  __bf16* ybr = yb + (size_t)row*EE;
  ybr[t]=(__bf16)o0; ybr[t+256]=(__bf16)o1; ybr[t+512]=(__bf16)o2;
}

// ---------------- sinusoidal emb + time MLP (tiny) ----------------
__global__ void sinemb_kernel(const int* __restrict__ timesteps, float* __restrict__ emb){
  int i = blockIdx.x*256+threadIdx.x;
  if (i >= NB*EE) return;
  int b = i/EE, e = i - b*EE;
  int half = EE/2;
  int j = (e<half)? e : e-half;
  float freq = expf(-logf(10000.f)*(float)j/(float)half);
  float arg = (float)timesteps[b]*freq;
  emb[i] = (e<half)? sinf(arg) : cosf(arg);
}

__global__ void time_mlp1(const float* __restrict__ emb, const float* __restrict__ w1,
                          const float* __restrict__ b1, float* __restrict__ thid){
  int i = blockIdx.x*256+threadIdx.x;
  if (i >= NB*NH) return;
  int b = i/NH, h = i - b*NH;
  const float* er = emb + b*EE;
  const float* wr = w1 + (size_t)h*EE;
  float s = 0.f;
  for (int e=0;e<EE;e++) s = fmaf(er[e], wr[e], s);
  s += b1[h];
  thid[i] = s/(1.f+expf(-s));
}

__global__ void time_mlp2(const float* __restrict__ thid, const float* __restrict__ w2,
                          const float* __restrict__ b2, float* __restrict__ temb){
  int i = blockIdx.x*256+threadIdx.x;
  if (i >= NB*EE) return;
  int b = i/EE, e = i - b*EE;
  const float* tr = thid + b*NH;
  const float* wr = w2 + (size_t)e*NH;
  float s = 0.f;
  for (int h=0;h<NH;h++) s = fmaf(tr[h], wr[h], s);
  temb[i] = s + b2[e];
}

// ---------------- embedding ----------------
__global__ void embed_kernel(const int* __restrict__ tokens, const float* __restrict__ tok_emb,
                             const float* __restrict__ temb, float* __restrict__ x){
  int idx = blockIdx.x*256+threadIdx.x;
  int e = idx % EE; int bl = idx / EE; int b = bl / NL;
  int tok = tokens[bl];
  x[idx] = tok_emb[(size_t)tok*EE + e] + temb[b*EE + e];
}

// ---------------- depthwise causal conv (K=4) + SiLU ----------------
__global__ void conv_silu(const float* __restrict__ xn, const float* __restrict__ w, float* __restrict__ u){
  int idx = blockIdx.x*256+threadIdx.x;
  int e = idx % EE; int bl = idx / EE; int l = bl % NL;
  float acc = 0.f;
  #pragma unroll
  for (int k=0;k<4;k++){
    int ls = l-3+k;
    if (ls >= 0) acc = fmaf(w[e*4+k], xn[(size_t)(bl-3+k)*EE + e], acc);
  }
  u[idx] = acc/(1.f+expf(-acc));
}

// ---------------- chunked parallel scan ----------------
// recurrence: h[t] = a[t]*h[t-1] + s[t], a[0]=0; a[t]=exp(dt[t-1]*A), s[t]=bt(dt[t-1])*u[t-1]
__device__ __forceinline__ void scan_coef(const float* dt, const float* u, int b, int tt, int e,
                                          float A, float invA, bool small_, float& a, float& s){
  if (tt == 0){
    size_t idx = (size_t)(b*NL)*EE + e;
    float dtv = dt[idx], uv = u[idx];
    float at = expf(dtv*A);
    float bt = small_ ? dtv : (at-1.f)*invA;
    a = 0.f; s = bt*uv;
  } else {
    size_t idx = (size_t)(b*NL + tt-1)*EE + e;
    float dtv = dt[idx], uv = u[idx];
    float at = expf(dtv*A);
    float bt = small_ ? dtv : (at-1.f)*invA;
    a = at; s = bt*uv;
  }
}

__global__ __launch_bounds__(256) void scan_pass1(const float* __restrict__ dt,
    const float* __restrict__ u, const float* __restrict__ A_log,
    float* __restrict__ P, float* __restrict__ S)
{
  int t = blockIdx.x*256 + threadIdx.x;
  int n = t & 15;
  int rest = t >> 4;
  int e = rest % EE;
  int cb = rest / EE;
  int b = cb & 1;
  int c = cb >> 1;
  float A = -expf(A_log[e*NS+n]);
  float invA = 1.f/(A + 1e-10f);
  bool small_ = fabsf(A) < 1e-5f;
  float h = 0.f, p = 1.f;
  int base = c*CL;
  for (int i=0;i<CL;i++){
    float a, s;
    scan_coef(dt, u, b, base+i, e, A, invA, small_, a, s);
    p *= a; h = a*h + s;
  }
  int chain = (b*EE + e)*NS + n;
  P[chain*NC + c] = p;
  S[chain*NC + c] = h;
}

__global__ void scan_combine(const float* __restrict__ P, const float* __restrict__ S,
                             float* __restrict__ Hin){
  int chain = blockIdx.x*256 + threadIdx.x;   // B*E*NS = 24576
  float h = 0.f;
  #pragma unroll
  for (int c=0;c<NC;c++){
    Hin[chain*NC + c] = h;
    h = P[chain*NC + c]*h + S[chain*NC + c];
  }
}

__global__ __launch_bounds__(256) void scan_pass2(const float* __restrict__ dt,
    const float* __restrict__ u, const float* __restrict__ params, const float* __restrict__ z,
    const float* __restrict__ A_log, const float* __restrict__ Dp,
    const float* __restrict__ Hin, __bf16* __restrict__ gb)
{
  int t = blockIdx.x*256 + threadIdx.x;
  int n = t & 15;
  int rest = t >> 4;
  int e = rest % EE;
  int cb = rest / EE;
  int b = cb & 1;
  int c = cb >> 1;
  float A = -expf(A_log[e*NS+n]);
  float invA = 1.f/(A + 1e-10f);
  bool small_ = fabsf(A) < 1e-5f;
  int chain = (b*EE + e)*NS + n;
  float h = Hin[chain*NC + c];
  float Dv = Dp[e];
  int base = c*CL;
  for (int i=0;i<CL;i++){
    int tt = base + i;
    float a, s;
    scan_coef(dt, u, b, tt, e, A, invA, small_, a, s);
    h = a*h + s;
    float cp = params[(size_t)(b*NL + tt)*80 + 64 + n];
    float v = cp*h;
    v += __shfl_xor(v, 1, 16);
    v += __shfl_xor(v, 2, 16);
    v += __shfl_xor(v, 4, 16);
    v += __shfl_xor(v, 8, 16);
    if (n == 0){
      size_t idx = (size_t)(b*NL + tt)*EE + e;
      float uv = u[idx];
      float zv = z[idx];
      float sz = zv/(1.f+expf(-zv));
      gb[idx] = (__bf16)((v + uv*Dv)*sz);
    }
  }
}

extern "C" void kernel_launch(void* const* d_in, const int* in_sizes, int n_in,
                              void* d_out, int out_size, void* d_ws, size_t ws_size,
                              hipStream_t stream) {
  const int*   tokens    = (const int*)d_in[0];
  const int*   timesteps = (const int*)d_in[1];
  const float* tok_emb   = (const float*)d_in[2];
  const float* time_w1   = (const float*)d_in[3];
  const float* time_b1   = (const float*)d_in[4];
  const float* time_w2   = (const float*)d_in[5];
  const float* time_b2   = (const float*)d_in[6];
  const float* ln1_g     = (const float*)d_in[7];
  const float* ln1_b     = (const float*)d_in[8];
  const float* z_w       = (const float*)d_in[9];
  const float* p_w       = (const float*)d_in[10];
  const float* conv_w    = (const float*)d_in[11];
  const float* dtp_w     = (const float*)d_in[12];
  const float* dtp_b     = (const float*)d_in[13];
  const float* A_log     = (const float*)d_in[14];
  const float* D_param   = (const float*)d_in[15];
  const float* out_w     = (const float*)d_in[16];
  const float* ln2_g     = (const float*)d_in[17];
  const float* ln2_b     = (const float*)d_in[18];
  const float* mlp_w1    = (const float*)d_in[19];
  const float* mlp_b1    = (const float*)d_in[20];
  const float* mlp_w2    = (const float*)d_in[21];
  const float* mlp_b2    = (const float*)d_in[22];
  const float* lnout_g   = (const float*)d_in[23];
  const float* lnout_b   = (const float*)d_in[24];
  const float* head_w    = (const float*)d_in[25];
  const float* head_b    = (const float*)d_in[26];
  float* out = (float*)d_out;

  float* ws = (float*)d_ws;
  float* x      = ws;
  float* xn     = x   + (size_t)M_ROWS*EE;
  float* z      = xn  + (size_t)M_ROWS*EE;
  float* dt     = z   + (size_t)M_ROWS*EE;
  float* u      = dt  + (size_t)M_ROWS*EE;
  float* params = u   + (size_t)M_ROWS*EE;
  float* P      = params + (size_t)M_ROWS*80;
  float* S      = P   + (size_t)NB*EE*NS*NC;
  float* Hin    = S   + (size_t)NB*EE*NS*NC;
  float* emb    = Hin + (size_t)NB*EE*NS*NC;
  float* thid   = emb + NB*EE;
  __bf16* xnb   = (__bf16*)(thid + NB*NH);
  __bf16* gb    = xnb + (size_t)M_ROWS*EE;
  __bf16* hidb  = gb  + (size_t)M_ROWS*EE;
  __bf16* wb    = hidb + (size_t)M_ROWS*NH;   // 24.576M bf16 max (head)

  sinemb_kernel<<<(NB*EE+255)/256, 256, 0, stream>>>(timesteps, emb);
  time_mlp1<<<(NB*NH+255)/256, 256, 0, stream>>>(emb, time_w1, time_b1, thid);
  time_mlp2<<<(NB*EE+255)/256, 256, 0, stream>>>(thid, time_w2, time_b2, emb);
  embed_kernel<<<M_ROWS*EE/256, 256, 0, stream>>>(tokens, tok_emb, emb, x);

  const int scan_grid = NB*EE*NS*NC/256;   // 1536

  for (int i=0;i<NDEPTH;i++){
    ln_kernel<<<M_ROWS, 256, 0, stream>>>(x, ln1_g + i*EE, ln1_b + i*EE, xn, xnb);
    // z = xn @ z_w^T (bf16 MFMA)
    conv_f2b<<<(EE*EE/4+255)/256, 256, 0, stream>>>(z_w + (size_t)i*EE*EE, wb, EE*EE);
    gemm_bf16<BE_STORE><<<dim3(EE/128, M_ROWS/128), 256, 0, stream>>>(xnb, wb, nullptr, z, EE, EE);
    // params = xn @ p_w^T (fp32, N=80)
    gemm_wt<EPI_STORE><<<dim3(2, M_ROWS/64), 256, 0, stream>>>(
        xn, EE, p_w + (size_t)i*80*EE, nullptr, params, 80, 80, EE);
    // dt = softplus(params[:, :48] @ dtp_w^T + b) (fp32, K=48)
    gemm_wt<EPI_SOFTPLUS_BIAS><<<dim3(EE/64, M_ROWS/64), 256, 0, stream>>>(
        params, 80, dtp_w + (size_t)i*EE*RR, dtp_b + i*EE, dt, EE, EE, RR);
    conv_silu<<<M_ROWS*EE/256, 256, 0, stream>>>(xn, conv_w + (size_t)i*EE*4, u);
    // chunked scan -> gb (bf16)
    scan_pass1<<<scan_grid, 256, 0, stream>>>(dt, u, A_log + (size_t)i*EE*NS, P, S);
    scan_combine<<<NB*EE*NS/256, 256, 0, stream>>>(P, S, Hin);
    scan_pass2<<<scan_grid, 256, 0, stream>>>(dt, u, params, z,
        A_log + (size_t)i*EE*NS, D_param + i*EE, Hin, gb);
    // x += gb @ out_w^T
    conv_f2b<<<(EE*EE/4+255)/256, 256, 0, stream>>>(out_w + (size_t)i*EE*EE, wb, EE*EE);
    gemm_bf16<BE_RESID><<<dim3(EE/128, M_ROWS/128), 256, 0, stream>>>(gb, wb, nullptr, x, EE, EE);
    // MLP
    ln_kernel<<<M_ROWS, 256, 0, stream>>>(x, ln2_g + i*EE, ln2_b + i*EE, nullptr, xnb);
    conv_f2b<<<(NH*EE/4+255)/256, 256, 0, stream>>>(mlp_w1 + (size_t)i*NH*EE, wb, NH*EE);
    gemm_bf16<BE_BIAS_GELU_B16><<<dim3(NH/128, M_ROWS/128), 256, 0, stream>>>(
        xnb, wb, mlp_b1 + i*NH, hidb, NH, EE);
    conv_f2b<<<(EE*NH/4+255)/256, 256, 0, stream>>>(mlp_w2 + (size_t)i*EE*NH, wb, EE*NH);
    gemm_bf16<BE_BIAS_RESID><<<dim3(EE/128, M_ROWS/128), 256, 0, stream>>>(
        hidb, wb, mlp_b2 + i*EE, x, EE, NH);
  }
  ln_kernel<<<M_ROWS, 256, 0, stream>>>(x, lnout_g, lnout_b, nullptr, xnb);
  conv_f2b<<<(NV*EE/4+255)/256, 256, 0, stream>>>(head_w, wb, NV*EE);
  gemm_bf16<BE_BIAS><<<dim3(NV/128, M_ROWS/128), 256, 0, stream>>>(xnb, wb, head_b, out, NV, EE);
}

// Round 3
// 1521.699 us; speedup vs baseline: 5.2543x; 1.2126x over previous
//
#include <hip/hip_runtime.h>
#include <math.h>

#define EE 768
#define NS 16
#define RR 48
#define NDEPTH 4
#define NB 2
#define NL 1024
#define NH 3072
#define NV 32000
#define M_ROWS (NB*NL)   // 2048
#define NC 32            // scan chunks
#define CL 32            // chunk length

typedef __attribute__((ext_vector_type(8))) __bf16 bf16x8;
typedef __attribute__((ext_vector_type(4))) __bf16 bf16x4;
typedef __attribute__((ext_vector_type(4))) float f32x4;

__device__ __forceinline__ void gl_lds16(const __bf16* g, __bf16* l){
  __builtin_amdgcn_global_load_lds(
      (const __attribute__((address_space(1))) void*)g,
      (__attribute__((address_space(3))) void*)l, 16, 0, 0);
}

// ---------------- bf16 MFMA GEMM: C = A @ W^T (+epilogues) ----------------
// A: M x K bf16 row-major, W: N x K bf16 row-major. M mult of 128, N mult of 128, K mult of 32.
enum { BE_STORE=0, BE_BIAS=1, BE_RESID=2, BE_BIAS_RESID=3, BE_BIAS_GELU_B16=4 };

template<int EPI>
__global__ __launch_bounds__(256) void gemm_bf16(const __bf16* __restrict__ A,
    const __bf16* __restrict__ W, const float* __restrict__ bias,
    void* __restrict__ Cv, int N, int K, int gx, int gy)
{
  // ---- block remap: bijective XCD swizzle (m204) then N-chunked (GN) ordering ----
  const int nwg = gx*gy;
  const int orig = blockIdx.x;
  const int q = nwg >> 3, r = nwg & 7;
  const int xcd = orig & 7, bse = orig >> 3;
  int wg = (xcd < r ? xcd*(q+1) : r*(q+1) + (xcd-r)*q) + bse;
  const int GN = 16;
  const int per = gy*GN;
  const int g = wg / per;
  const int gstart = g*GN;
  const int gw0 = gx - gstart;
  const int gw = (GN < gw0) ? GN : gw0;
  const int local = wg - g*per;
  const int bx = gstart + local % gw;
  const int by = local / gw;

  __shared__ __bf16 As[128][32];
  __shared__ __bf16 Ws[128][32];
  const int bm = by*128, bn = bx*128;
  const int tid = threadIdx.x;
  const int w = tid>>6, lane = tid&63;
  const int wr = w>>1, wc = w&1;
  const int fr = lane&15, kg = lane>>4;
  const int srow = lane>>2;
  // staging k-slice XOR pre-swizzle (content at LDS (row,s) = k-slice s^((row>>1)&3))
  const int ks = (lane&3) ^ ((srow>>1)&3);
  // read-side slot for logical k-group kg at row ...+fr
  const int sxor = kg ^ ((fr>>1)&3);

  f32x4 acc[4][4];
  #pragma unroll
  for (int m=0;m<4;m++)
    #pragma unroll
    for (int n=0;n<4;n++)
      acc[m][n] = (f32x4){0.f,0.f,0.f,0.f};

  for (int k0=0;k0<K;k0+=32){
    const __bf16* gA = A + (size_t)(bm + w*32 + srow)*K + k0 + ks*8;
    const __bf16* gW = W + (size_t)(bn + w*32 + srow)*K + k0 + ks*8;
    gl_lds16(gA,                 &As[w*32][0]);
    gl_lds16(gA + (size_t)16*K,  &As[w*32+16][0]);
    gl_lds16(gW,                 &Ws[w*32][0]);
    gl_lds16(gW + (size_t)16*K,  &Ws[w*32+16][0]);
    __syncthreads();
    bf16x8 af[4], bfr[4];
    #pragma unroll
    for (int m=0;m<4;m++) af[m]  = *(const bf16x8*)&As[wr*64 + m*16 + fr][sxor*8];
    #pragma unroll
    for (int n=0;n<4;n++) bfr[n] = *(const bf16x8*)&Ws[wc*64 + n*16 + fr][sxor*8];
    #pragma unroll
    for (int m=0;m<4;m++)
      #pragma unroll
      for (int n=0;n<4;n++)
        acc[m][n] = __builtin_amdgcn_mfma_f32_16x16x32_bf16(af[m], bfr[n], acc[m][n], 0,0,0);
    __syncthreads();
  }

  float* Cf = (float*)Cv;
  __bf16* Cb = (__bf16*)Cv;
  #pragma unroll
  for (int m=0;m<4;m++){
    int row = bm + wr*64 + m*16 + kg*4;
    #pragma unroll
    for (int n=0;n<4;n++){
      int col = bn + wc*64 + n*16 + fr;
      float bsv = 0.f;
      if (EPI==BE_BIAS || EPI==BE_BIAS_RESID || EPI==BE_BIAS_GELU_B16) bsv = bias[col];
      #pragma unroll
      for (int rr=0;rr<4;rr++){
        float v = acc[m][n][rr];
        size_t idx = (size_t)(row+rr)*N + col;
        if (EPI==BE_STORE)            Cf[idx] = v;
        else if (EPI==BE_BIAS)        Cf[idx] = v + bsv;
        else if (EPI==BE_RESID)       Cf[idx] += v;
        else if (EPI==BE_BIAS_RESID)  Cf[idx] += v + bsv;
        else { float xg = v + bsv; Cb[idx] = (__bf16)(0.5f*xg*(1.f+erff(xg*0.70710678118654752f))); }
      }
    }
  }
}

// ---------------- fp32->bf16 convert ----------------
__global__ void conv_f2b(const float* __restrict__ w, __bf16* __restrict__ o, int nelem){
  int i = (blockIdx.x*256 + threadIdx.x)*4;
  if (i >= nelem) return;
  float4 v = *(const float4*)(w+i);
  bf16x4 r = { (__bf16)v.x, (__bf16)v.y, (__bf16)v.z, (__bf16)v.w };
  *(bf16x4*)(o+i) = r;
}

// ---------------- fp32 GEMM (small: p_w N=80, dtp K=48) ----------------
enum { EPI_STORE=0, EPI_SOFTPLUS_BIAS=3 };

template<int EPI>
__global__ __launch_bounds__(256) void gemm_wt(const float* __restrict__ A, int lda,
    const float* __restrict__ W, const float* __restrict__ bias,
    float* __restrict__ C, int ldc, int N, int K)
{
  __shared__ __align__(16) float Asf[16][68];
  __shared__ __align__(16) float Wsf[16][68];
  const int bm = blockIdx.y*64, bn = blockIdx.x*64;
  const int t = threadIdx.x;
  const int lr = t>>2;
  const int lk = (t&3)<<2;
  const int ty = t>>4, tx = t&15;
  float acc[4][4] = {};
  for (int k0=0;k0<K;k0+=16){
    float4 av = *(const float4*)(A + (size_t)(bm+lr)*lda + k0 + lk);
    float4 wv = make_float4(0.f,0.f,0.f,0.f);
    if (bn+lr < N) wv = *(const float4*)(W + (size_t)(bn+lr)*K + k0 + lk);
    __syncthreads();
    Asf[lk+0][lr]=av.x; Asf[lk+1][lr]=av.y; Asf[lk+2][lr]=av.z; Asf[lk+3][lr]=av.w;
    Wsf[lk+0][lr]=wv.x; Wsf[lk+1][lr]=wv.y; Wsf[lk+2][lr]=wv.z; Wsf[lk+3][lr]=wv.w;
    __syncthreads();
    #pragma unroll
    for (int kk=0;kk<16;kk++){
      float4 a = *(const float4*)&Asf[kk][ty<<2];
      float4 b = *(const float4*)&Wsf[kk][tx<<2];
      float ar[4] = {a.x,a.y,a.z,a.w};
      float br[4] = {b.x,b.y,b.z,b.w};
      #pragma unroll
      for (int i=0;i<4;i++)
        #pragma unroll
        for (int j=0;j<4;j++)
          acc[i][j] = fmaf(ar[i], br[j], acc[i][j]);
    }
  }
  #pragma unroll
  for (int i=0;i<4;i++){
    int row = bm + (ty<<2) + i;
    #pragma unroll
    for (int j=0;j<4;j++){
      int col = bn + (tx<<2) + j;
      if (col >= N) continue;
      float v = acc[i][j];
      size_t idx = (size_t)row*ldc + col;
      if (EPI==EPI_STORE) C[idx]=v;
      else { float xg=v+bias[col]; C[idx]=fmaxf(xg,0.f)+log1pf(expf(-fabsf(xg))); }
    }
  }
}

// ---------------- LayerNorm (row = 768): fp32 out (nullable) + bf16 out ----------------
__global__ __launch_bounds__(256) void ln_kernel(const float* __restrict__ x,
    const float* __restrict__ gp, const float* __restrict__ bp,
    float* __restrict__ y, __bf16* __restrict__ yb)
{
  int row = blockIdx.x;
  const float* xr = x + (size_t)row*EE;
  int t = threadIdx.x;
  float v0 = xr[t], v1 = xr[t+256], v2 = xr[t+512];
  float s = v0+v1+v2;
  #pragma unroll
  for (int m=1;m<64;m<<=1) s += __shfl_xor(s, m, 64);
  __shared__ float red[4], red2[4];
  int wid = t>>6;
  if ((t&63)==0) red[wid]=s;
  __syncthreads();
  float mu = (red[0]+red[1]+red[2]+red[3]) * (1.f/768.f);
  float d0=v0-mu, d1=v1-mu, d2=v2-mu;
  float qq = d0*d0+d1*d1+d2*d2;
  #pragma unroll
  for (int m=1;m<64;m<<=1) qq += __shfl_xor(qq, m, 64);
  if ((t&63)==0) red2[wid]=qq;
  __syncthreads();
  float var = (red2[0]+red2[1]+red2[2]+red2[3]) * (1.f/768.f);
  float inv = 1.0f/sqrtf(var + 1e-5f);
  float o0 = d0*inv*gp[t]     + bp[t];
  float o1 = d1*inv*gp[t+256] + bp[t+256];
  float o2 = d2*inv*gp[t+512] + bp[t+512];
  if (y){
    float* yr = y + (size_t)row*EE;
    yr[t]=o0; yr[t+256]=o1; yr[t+512]=o2;
  }
  __bf16* ybr = yb + (size_t)row*EE;
  ybr[t]=(__bf16)o0; ybr[t+256]=(__bf16)o1; ybr[t+512]=(__bf16)o2;
}

// ---------------- sinusoidal emb + time MLP (wave-per-row, coalesced) ----------------
__global__ void sinemb_kernel(const int* __restrict__ timesteps, float* __restrict__ emb){
  int i = blockIdx.x*256+threadIdx.x;
  if (i >= NB*EE) return;
  int b = i/EE, e = i - b*EE;
  int half = EE/2;
  int j = (e<half)? e : e-half;
  float freq = expf(-logf(10000.f)*(float)j/(float)half);
  float arg = (float)timesteps[b]*freq;
  emb[i] = (e<half)? sinf(arg) : cosf(arg);
}

__global__ void time_mlp1(const float* __restrict__ emb, const float* __restrict__ w1,
                          const float* __restrict__ b1, float* __restrict__ thid){
  int wid = (blockIdx.x*256 + threadIdx.x)>>6;   // 0..NB*NH-1
  int lane = threadIdx.x & 63;
  int b = wid / NH, h = wid - b*NH;
  const float* er = emb + b*EE;
  const float* wr = w1 + (size_t)h*EE;
  float s = 0.f;
  #pragma unroll
  for (int j=0;j<EE/64;j++) s = fmaf(er[j*64+lane], wr[j*64+lane], s);
  #pragma unroll
  for (int m=1;m<64;m<<=1) s += __shfl_xor(s, m, 64);
  if (lane==0){
    s += b1[h];
    thid[wid] = s/(1.f+expf(-s));
  }
}

__global__ void time_mlp2(const float* __restrict__ thid, const float* __restrict__ w2,
                          const float* __restrict__ b2, float* __restrict__ temb){
  int wid = (blockIdx.x*256 + threadIdx.x)>>6;   // 0..NB*EE-1
  int lane = threadIdx.x & 63;
  int b = wid / EE, e = wid - b*EE;
  const float* tr = thid + b*NH;
  const float* wr = w2 + (size_t)e*NH;
  float s = 0.f;
  #pragma unroll
  for (int j=0;j<NH/64;j++) s = fmaf(tr[j*64+lane], wr[j*64+lane], s);
  #pragma unroll
  for (int m=1;m<64;m<<=1) s += __shfl_xor(s, m, 64);
  if (lane==0) temb[wid] = s + b2[e];
}

// ---------------- embedding ----------------
__global__ void embed_kernel(const int* __restrict__ tokens, const float* __restrict__ tok_emb,
                             const float* __restrict__ temb, float* __restrict__ x){
  int idx = blockIdx.x*256+threadIdx.x;
  int e = idx % EE; int bl = idx / EE; int b = bl / NL;
  int tok = tokens[bl];
  x[idx] = tok_emb[(size_t)tok*EE + e] + temb[b*EE + e];
}

// ---------------- depthwise causal conv (K=4) + SiLU ----------------
__global__ void conv_silu(const float* __restrict__ xn, const float* __restrict__ w, float* __restrict__ u){
  int idx = blockIdx.x*256+threadIdx.x;
  int e = idx % EE; int bl = idx / EE; int l = bl % NL;
  float acc = 0.f;
  #pragma unroll
  for (int k=0;k<4;k++){
    int ls = l-3+k;
    if (ls >= 0) acc = fmaf(w[e*4+k], xn[(size_t)(bl-3+k)*EE + e], acc);
  }
  u[idx] = acc/(1.f+expf(-acc));
}

// ---------------- chunked parallel scan: thread per (b,e,chunk), 16 states in regs ----------------
// recurrence: h[t] = a[t]*h[t-1] + s[t]; a[0]=0; a[t]=exp(dt[t-1]*A), s[t]=bt(dt[t-1])*u[t-1]
__global__ __launch_bounds__(256) void scan_pass1(const float* __restrict__ dt,
    const float* __restrict__ u, const float* __restrict__ A_log,
    float* __restrict__ P, float* __restrict__ S)
{
  int t = blockIdx.x*256 + threadIdx.x;        // B*E*NC threads
  int e = t % EE;
  int cb = t / EE;
  int c = cb & (NC-1), b = cb >> 5;
  float Av[NS], iAv[NS], h[NS], p[NS];
  #pragma unroll
  for (int n4=0;n4<4;n4++){
    float4 v = *(const float4*)(A_log + (size_t)e*NS + n4*4);
    float a0=-expf(v.x), a1=-expf(v.y), a2=-expf(v.z), a3=-expf(v.w);
    Av[n4*4+0]=a0; Av[n4*4+1]=a1; Av[n4*4+2]=a2; Av[n4*4+3]=a3;
    iAv[n4*4+0]=1.f/(a0+1e-10f); iAv[n4*4+1]=1.f/(a1+1e-10f);
    iAv[n4*4+2]=1.f/(a2+1e-10f); iAv[n4*4+3]=1.f/(a3+1e-10f);
  }
  #pragma unroll
  for (int n=0;n<NS;n++){ h[n]=0.f; p[n]=1.f; }
  const int base = c*CL;
  for (int i=0;i<CL;i++){
    int tt = base+i;
    size_t src = (size_t)(b*NL + (tt==0?0:tt-1))*EE + e;
    float dtv = dt[src], uv = u[src];
    if (tt==0){
      #pragma unroll
      for (int n=0;n<NS;n++){
        float at = expf(dtv*Av[n]);
        float bt = (fabsf(Av[n])<1e-5f)? dtv : (at-1.f)*iAv[n];
        h[n] = bt*uv; p[n] = 0.f;
      }
    } else {
      #pragma unroll
      for (int n=0;n<NS;n++){
        float at = expf(dtv*Av[n]);
        float bt = (fabsf(Av[n])<1e-5f)? dtv : (at-1.f)*iAv[n];
        h[n] = fmaf(at, h[n], bt*uv);
        p[n] *= at;
      }
    }
  }
  size_t o = ((size_t)(b*EE + e)*NC + c)*NS;
  #pragma unroll
  for (int n4=0;n4<4;n4++){
    *(float4*)&P[o+n4*4] = make_float4(p[n4*4],p[n4*4+1],p[n4*4+2],p[n4*4+3]);
    *(float4*)&S[o+n4*4] = make_float4(h[n4*4],h[n4*4+1],h[n4*4+2],h[n4*4+3]);
  }
}

__global__ void scan_combine(const float* __restrict__ P, const float* __restrict__ S,
                             float* __restrict__ Hin){
  int t = blockIdx.x*256 + threadIdx.x;   // B*E*NS threads, n fastest
  int n = t & 15; int ec = t >> 4;
  float h = 0.f;
  size_t base = (size_t)ec*NC*NS + n;
  #pragma unroll
  for (int c=0;c<NC;c++){
    Hin[base + c*NS] = h;
    h = P[base + c*NS]*h + S[base + c*NS];
  }
}

__global__ __launch_bounds__(256) void scan_pass2(const float* __restrict__ dt,
    const float* __restrict__ u, const float* __restrict__ params, const float* __restrict__ z,
    const float* __restrict__ A_log, const float* __restrict__ Dp,
    const float* __restrict__ Hin, __bf16* __restrict__ gb)
{
  int t = blockIdx.x*256 + threadIdx.x;
  int e = t % EE;
  int cb = t / EE;
  int c = cb & (NC-1), b = cb >> 5;
  float Av[NS], iAv[NS], h[NS];
  #pragma unroll
  for (int n4=0;n4<4;n4++){
    float4 v = *(const float4*)(A_log + (size_t)e*NS + n4*4);
    float a0=-expf(v.x), a1=-expf(v.y), a2=-expf(v.z), a3=-expf(v.w);
    Av[n4*4+0]=a0; Av[n4*4+1]=a1; Av[n4*4+2]=a2; Av[n4*4+3]=a3;
    iAv[n4*4+0]=1.f/(a0+1e-10f); iAv[n4*4+1]=1.f/(a1+1e-10f);
    iAv[n4*4+2]=1.f/(a2+1e-10f); iAv[n4*4+3]=1.f/(a3+1e-10f);
  }
  size_t hb = ((size_t)(b*EE + e)*NC + c)*NS;
  #pragma unroll
  for (int n4=0;n4<4;n4++){
    float4 v = *(const float4*)&Hin[hb+n4*4];
    h[n4*4]=v.x; h[n4*4+1]=v.y; h[n4*4+2]=v.z; h[n4*4+3]=v.w;
  }
  float Dv = Dp[e];
  const int base = c*CL;
  for (int i=0;i<CL;i++){
    int tt = base+i;
    size_t src = (size_t)(b*NL + (tt==0?0:tt-1))*EE + e;
    float dtv = dt[src], uv = u[src];
    if (tt==0){
      #pragma unroll
      for (int n=0;n<NS;n++){
        float at = expf(dtv*Av[n]);
        float bt = (fabsf(Av[n])<1e-5f)? dtv : (at-1.f)*iAv[n];
        h[n] = bt*uv;
      }
    } else {
      #pragma unroll
      for (int n=0;n<NS;n++){
        float at = expf(dtv*Av[n]);
        float bt = (fabsf(Av[n])<1e-5f)? dtv : (at-1.f)*iAv[n];
        h[n] = fmaf(at, h[n], bt*uv);
      }
    }
    const float* cr = params + (size_t)(b*NL+tt)*80 + 64;
    float y = 0.f;
    #pragma unroll
    for (int n4=0;n4<4;n4++){
      float4 cv = *(const float4*)(cr + n4*4);
      y = fmaf(cv.x, h[n4*4], y); y = fmaf(cv.y, h[n4*4+1], y);
      y = fmaf(cv.z, h[n4*4+2], y); y = fmaf(cv.w, h[n4*4+3], y);
    }
    size_t cidx = (size_t)(b*NL+tt)*EE + e;
    float ucur = u[cidx];
    float zv = z[cidx];
    float sz = zv/(1.f+expf(-zv));
    gb[cidx] = (__bf16)((y + ucur*Dv)*sz);
  }
}

extern "C" void kernel_launch(void* const* d_in, const int* in_sizes, int n_in,
                              void* d_out, int out_size, void* d_ws, size_t ws_size,
                              hipStream_t stream) {
  const int*   tokens    = (const int*)d_in[0];
  const int*   timesteps = (const int*)d_in[1];
  const float* tok_emb   = (const float*)d_in[2];
  const float* time_w1   = (const float*)d_in[3];
  const float* time_b1   = (const float*)d_in[4];
  const float* time_w2   = (const float*)d_in[5];
  const float* time_b2   = (const float*)d_in[6];
  const float* ln1_g     = (const float*)d_in[7];
  const float* ln1_b     = (const float*)d_in[8];
  const float* z_w       = (const float*)d_in[9];
  const float* p_w       = (const float*)d_in[10];
  const float* conv_w    = (const float*)d_in[11];
  const float* dtp_w     = (const float*)d_in[12];
  const float* dtp_b     = (const float*)d_in[13];
  const float* A_log     = (const float*)d_in[14];
  const float* D_param   = (const float*)d_in[15];
  const float* out_w     = (const float*)d_in[16];
  const float* ln2_g     = (const float*)d_in[17];
  const float* ln2_b     = (const float*)d_in[18];
  const float* mlp_w1    = (const float*)d_in[19];
  const float* mlp_b1    = (const float*)d_in[20];
  const float* mlp_w2    = (const float*)d_in[21];
  const float* mlp_b2    = (const float*)d_in[22];
  const float* lnout_g   = (const float*)d_in[23];
  const float* lnout_b   = (const float*)d_in[24];
  const float* head_w    = (const float*)d_in[25];
  const float* head_b    = (const float*)d_in[26];
  float* out = (float*)d_out;

  float* ws = (float*)d_ws;
  float* x      = ws;
  float* xn     = x   + (size_t)M_ROWS*EE;
  float* z      = xn  + (size_t)M_ROWS*EE;
  float* dt     = z   + (size_t)M_ROWS*EE;
  float* u      = dt  + (size_t)M_ROWS*EE;
  float* params = u   + (size_t)M_ROWS*EE;
  float* P      = params + (size_t)M_ROWS*80;
  float* S      = P   + (size_t)NB*EE*NS*NC;
  float* Hin    = S   + (size_t)NB*EE*NS*NC;
  float* emb    = Hin + (size_t)NB*EE*NS*NC;
  float* thid   = emb + NB*EE;
  __bf16* xnb   = (__bf16*)(thid + NB*NH);
  __bf16* gb    = xnb + (size_t)M_ROWS*EE;
  __bf16* hidb  = gb  + (size_t)M_ROWS*EE;
  __bf16* wb    = hidb + (size_t)M_ROWS*NH;

  sinemb_kernel<<<(NB*EE+255)/256, 256, 0, stream>>>(timesteps, emb);
  time_mlp1<<<NB*NH/4, 256, 0, stream>>>(emb, time_w1, time_b1, thid);
  time_mlp2<<<NB*EE/4, 256, 0, stream>>>(thid, time_w2, time_b2, emb);
  embed_kernel<<<M_ROWS*EE/256, 256, 0, stream>>>(tokens, tok_emb, emb, x);

  const int scan_grid = NB*EE*NC/256;       // 192
  const int comb_grid = NB*EE*NS/256;       // 96

  for (int i=0;i<NDEPTH;i++){
    ln_kernel<<<M_ROWS, 256, 0, stream>>>(x, ln1_g + i*EE, ln1_b + i*EE, xn, xnb);
    conv_f2b<<<(EE*EE/4+255)/256, 256, 0, stream>>>(z_w + (size_t)i*EE*EE, wb, EE*EE);
    gemm_bf16<BE_STORE><<<(EE/128)*(M_ROWS/128), 256, 0, stream>>>(xnb, wb, nullptr, z, EE, EE, EE/128, M_ROWS/128);
    gemm_wt<EPI_STORE><<<dim3(2, M_ROWS/64), 256, 0, stream>>>(
        xn, EE, p_w + (size_t)i*80*EE, nullptr, params, 80, 80, EE);
    gemm_wt<EPI_SOFTPLUS_BIAS><<<dim3(EE/64, M_ROWS/64), 256, 0, stream>>>(
        params, 80, dtp_w + (size_t)i*EE*RR, dtp_b + i*EE, dt, EE, EE, RR);
    conv_silu<<<M_ROWS*EE/256, 256, 0, stream>>>(xn, conv_w + (size_t)i*EE*4, u);
    scan_pass1<<<scan_grid, 256, 0, stream>>>(dt, u, A_log + (size_t)i*EE*NS, P, S);
    scan_combine<<<comb_grid, 256, 0, stream>>>(P, S, Hin);
    scan_pass2<<<scan_grid, 256, 0, stream>>>(dt, u, params, z,
        A_log + (size_t)i*EE*NS, D_param + i*EE, Hin, gb);
    conv_f2b<<<(EE*EE/4+255)/256, 256, 0, stream>>>(out_w + (size_t)i*EE*EE, wb, EE*EE);
    gemm_bf16<BE_RESID><<<(EE/128)*(M_ROWS/128), 256, 0, stream>>>(gb, wb, nullptr, x, EE, EE, EE/128, M_ROWS/128);
    ln_kernel<<<M_ROWS, 256, 0, stream>>>(x, ln2_g + i*EE, ln2_b + i*EE, nullptr, xnb);
    conv_f2b<<<(NH*EE/4+255)/256, 256, 0, stream>>>(mlp_w1 + (size_t)i*NH*EE, wb, NH*EE);
    gemm_bf16<BE_BIAS_GELU_B16><<<(NH/128)*(M_ROWS/128), 256, 0, stream>>>(
        xnb, wb, mlp_b1 + i*NH, hidb, NH, EE, NH/128, M_ROWS/128);
    conv_f2b<<<(EE*NH/4+255)/256, 256, 0, stream>>>(mlp_w2 + (size_t)i*EE*NH, wb, EE*NH);
    gemm_bf16<BE_BIAS_RESID><<<(EE/128)*(M_ROWS/128), 256, 0, stream>>>(
        hidb, wb, mlp_b2 + i*EE, x, EE, NH, EE/128, M_ROWS/128);
  }
  ln_kernel<<<M_ROWS, 256, 0, stream>>>(x, lnout_g, lnout_b, nullptr, xnb);
  conv_f2b<<<(NV*EE/4+255)/256, 256, 0, stream>>>(head_w, wb, NV*EE);
  gemm_bf16<BE_BIAS><<<(NV/128)*(M_ROWS/128), 256, 0, stream>>>(xnb, wb, head_b, out, NV, EE, NV/128, M_ROWS/128);
}

// Round 4
// 1148.754 us; speedup vs baseline: 6.9601x; 1.3247x over previous
//
#include <hip/hip_runtime.h>
#include <math.h>

#define EE 768
#define NS 16
#define RR 48
#define NDEPTH 4
#define NB 2
#define NL 1024
#define NH 3072
#define NV 32000
#define M_ROWS (NB*NL)   // 2048
#define NC 32            // scan chunks
#define CL 32            // chunk length
#define ZPW 896          // z(768) + dt_un(48) + Bu(16) + Cp(16) + pad(48)

typedef __attribute__((ext_vector_type(8))) __bf16 bf16x8;
typedef __attribute__((ext_vector_type(4))) __bf16 bf16x4;
typedef __attribute__((ext_vector_type(4))) float f32x4;

__device__ __forceinline__ void gl_lds16(const __bf16* g, __bf16* l){
  __builtin_amdgcn_global_load_lds(
      (const __attribute__((address_space(1))) void*)g,
      (__attribute__((address_space(3))) void*)l, 16, 0, 0);
}

// ---------------- bf16 MFMA GEMM: C = A @ W^T (+epilogues) ----------------
// A: M x K bf16 row-major, W: N x K bf16 row-major. M mult 128, N mult BNT, K mult 32.
enum { BE_STORE=0, BE_BIAS=1, BE_RESID=2, BE_BIAS_RESID=3, BE_BIAS_GELU_B16=4,
       BE_STORE_ZP=5, BE_SOFTPLUS=6 };

template<int EPI, int BNT>
__global__ __launch_bounds__(256) void gemm_bf16(const __bf16* __restrict__ A,
    const __bf16* __restrict__ W, const float* __restrict__ bias,
    void* __restrict__ Cv, __bf16* __restrict__ dtb, int N, int K, int gx, int gy)
{
  // bijective XCD swizzle (m204) then GN-grouped ordering for L2 W-reuse
  const int nwg = gx*gy;
  const int orig = blockIdx.x;
  const int q = nwg >> 3, r = nwg & 7;
  const int xcd = orig & 7, bse = orig >> 3;
  int wg = (xcd < r ? xcd*(q+1) : r*(q+1) + (xcd-r)*q) + bse;
  const int GN = 16;
  const int per = gy*GN;
  const int g = wg / per;
  const int gstart = g*GN;
  const int gw0 = gx - gstart;
  const int gw = (GN < gw0) ? GN : gw0;
  const int local = wg - g*per;
  const int bx = gstart + local % gw;
  const int by = local / gw;

  constexpr int NFR = BNT/32;
  __shared__ __bf16 As[128][32];
  __shared__ __bf16 Ws[BNT][32];
  const int bm = by*128, bn = bx*BNT;
  const int tid = threadIdx.x;
  const int w = tid>>6, lane = tid&63;
  const int wr = w>>1, wc = w&1;
  const int fr = lane&15, kg = lane>>4;
  const int srow = lane>>2;
  const int ks = (lane&3) ^ ((srow>>1)&3);   // pre-swizzled source k-slice
  const int sxor = kg ^ ((fr>>1)&3);         // swizzled read slot

  f32x4 acc[4][NFR];
  #pragma unroll
  for (int m=0;m<4;m++)
    #pragma unroll
    for (int n=0;n<NFR;n++)
      acc[m][n] = (f32x4){0.f,0.f,0.f,0.f};

  for (int k0=0;k0<K;k0+=32){
    const __bf16* gA = A + (size_t)(bm + w*32 + srow)*K + k0 + ks*8;
    gl_lds16(gA,                 &As[w*32][0]);
    gl_lds16(gA + (size_t)16*K,  &As[w*32+16][0]);
    if constexpr (BNT==128){
      const __bf16* gW = W + (size_t)(bn + w*32 + srow)*K + k0 + ks*8;
      gl_lds16(gW,                 &Ws[w*32][0]);
      gl_lds16(gW + (size_t)16*K,  &Ws[w*32+16][0]);
    } else {
      const __bf16* gW = W + (size_t)(bn + w*16 + srow)*K + k0 + ks*8;
      gl_lds16(gW, &Ws[w*16][0]);
    }
    __syncthreads();
    bf16x8 af[4], bfr[NFR];
    #pragma unroll
    for (int m=0;m<4;m++) af[m]  = *(const bf16x8*)&As[wr*64 + m*16 + fr][sxor*8];
    #pragma unroll
    for (int n=0;n<NFR;n++) bfr[n] = *(const bf16x8*)&Ws[wc*(BNT/2) + n*16 + fr][sxor*8];
    #pragma unroll
    for (int m=0;m<4;m++)
      #pragma unroll
      for (int n=0;n<NFR;n++)
        acc[m][n] = __builtin_amdgcn_mfma_f32_16x16x32_bf16(af[m], bfr[n], acc[m][n], 0,0,0);
    __syncthreads();
  }

  float* Cf = (float*)Cv;
  __bf16* Cb = (__bf16*)Cv;
  #pragma unroll
  for (int m=0;m<4;m++){
    int row = bm + wr*64 + m*16 + kg*4;
    #pragma unroll
    for (int n=0;n<NFR;n++){
      int col = bn + wc*(BNT/2) + n*16 + fr;
      float bsv = 0.f;
      if (EPI==BE_BIAS || EPI==BE_BIAS_RESID || EPI==BE_BIAS_GELU_B16 || EPI==BE_SOFTPLUS)
        bsv = bias[col];
      #pragma unroll
      for (int rr2=0;rr2<4;rr2++){
        float v = acc[m][n][rr2];
        size_t idx = (size_t)(row+rr2)*N + col;
        if (EPI==BE_STORE)            Cf[idx] = v;
        else if (EPI==BE_BIAS)        Cf[idx] = v + bsv;
        else if (EPI==BE_RESID)       Cf[idx] += v;
        else if (EPI==BE_BIAS_RESID)  Cf[idx] += v + bsv;
        else if (EPI==BE_BIAS_GELU_B16){
          float xg = v + bsv; Cb[idx] = (__bf16)(0.5f*xg*(1.f+erff(xg*0.70710678118654752f)));
        } else if (EPI==BE_STORE_ZP){
          Cf[idx] = v;
          if (col >= 768) dtb[(size_t)(row+rr2)*128 + (col-768)] = (__bf16)v;
        } else if (EPI==BE_SOFTPLUS){
          float xg = v + bsv; Cf[idx] = fmaxf(xg,0.f)+log1pf(expf(-fabsf(xg)));
        }
      }
    }
  }
}

// ---------------- weight conversion (once per call, start of graph) ----------------
__global__ void conv_f2b(const float* __restrict__ w, __bf16* __restrict__ o, int nelem){
  int i = (blockIdx.x*256 + threadIdx.x)*4;
  if (i >= nelem) return;
  float4 v = *(const float4*)(w+i);
  bf16x4 r = { (__bf16)v.x, (__bf16)v.y, (__bf16)v.z, (__bf16)v.w };
  *(bf16x4*)(o+i) = r;
}

__global__ void f2b_zp(const float* __restrict__ zw, const float* __restrict__ pw,
                       __bf16* __restrict__ o){
  int i4 = blockIdx.x*256 + threadIdx.x;          // 4-elem groups
  const int total = NDEPTH*ZPW*EE/4;
  if (i4 >= total) return;
  int idx = i4*4;
  int layer = idx / (ZPW*EE);
  int rem = idx - layer*(ZPW*EE);
  int row = rem / EE, col = rem - (rem/EE)*EE;
  float4 v;
  if (row < 768)      v = *(const float4*)(zw + ((size_t)layer*EE + row)*EE + col);
  else if (row < 848) v = *(const float4*)(pw + ((size_t)layer*80 + (row-768))*EE + col);
  else                v = make_float4(0.f,0.f,0.f,0.f);
  bf16x4 r = { (__bf16)v.x, (__bf16)v.y, (__bf16)v.z, (__bf16)v.w };
  *(bf16x4*)(o+idx) = r;
}

__global__ void f2b_dtp(const float* __restrict__ w, __bf16* __restrict__ o){
  int i4 = blockIdx.x*256 + threadIdx.x;
  const int total = NDEPTH*EE*128/4;
  if (i4 >= total) return;
  int idx = i4*4;
  int layer = idx / (EE*128);
  int rem = idx - layer*(EE*128);
  int row = rem / 128, col = rem & 127;
  float4 v = make_float4(0.f,0.f,0.f,0.f);
  if (col < RR) v = *(const float4*)(w + ((size_t)layer*EE + row)*RR + col);
  bf16x4 r = { (__bf16)v.x, (__bf16)v.y, (__bf16)v.z, (__bf16)v.w };
  *(bf16x4*)(o+idx) = r;
}

// ---------------- LayerNorm (row = 768) -> bf16 ----------------
__global__ __launch_bounds__(256) void ln_kernel(const float* __restrict__ x,
    const float* __restrict__ gp, const float* __restrict__ bp, __bf16* __restrict__ yb)
{
  int row = blockIdx.x;
  const float* xr = x + (size_t)row*EE;
  int t = threadIdx.x;
  float v0 = xr[t], v1 = xr[t+256], v2 = xr[t+512];
  float s = v0+v1+v2;
  #pragma unroll
  for (int m=1;m<64;m<<=1) s += __shfl_xor(s, m, 64);
  __shared__ float red[4], red2[4];
  int wid = t>>6;
  if ((t&63)==0) red[wid]=s;
  __syncthreads();
  float mu = (red[0]+red[1]+red[2]+red[3]) * (1.f/768.f);
  float d0=v0-mu, d1=v1-mu, d2=v2-mu;
  float qq = d0*d0+d1*d1+d2*d2;
  #pragma unroll
  for (int m=1;m<64;m<<=1) qq += __shfl_xor(qq, m, 64);
  if ((t&63)==0) red2[wid]=qq;
  __syncthreads();
  float var = (red2[0]+red2[1]+red2[2]+red2[3]) * (1.f/768.f);
  float inv = 1.0f/sqrtf(var + 1e-5f);
  __bf16* ybr = yb + (size_t)row*EE;
  ybr[t]     = (__bf16)(d0*inv*gp[t]     + bp[t]);
  ybr[t+256] = (__bf16)(d1*inv*gp[t+256] + bp[t+256]);
  ybr[t+512] = (__bf16)(d2*inv*gp[t+512] + bp[t+512]);
}

// ---------------- sinusoidal emb + time MLP (wave-per-row) ----------------
__global__ void sinemb_kernel(const int* __restrict__ timesteps, float* __restrict__ emb){
  int i = blockIdx.x*256+threadIdx.x;
  if (i >= NB*EE) return;
  int b = i/EE, e = i - b*EE;
  int half = EE/2;
  int j = (e<half)? e : e-half;
  float freq = expf(-logf(10000.f)*(float)j/(float)half);
  float arg = (float)timesteps[b]*freq;
  emb[i] = (e<half)? sinf(arg) : cosf(arg);
}

__global__ void time_mlp1(const float* __restrict__ emb, const float* __restrict__ w1,
                          const float* __restrict__ b1, float* __restrict__ thid){
  int wid = (blockIdx.x*256 + threadIdx.x)>>6;
  int lane = threadIdx.x & 63;
  int b = wid / NH, h = wid - b*NH;
  const float* er = emb + b*EE;
  const float* wr = w1 + (size_t)h*EE;
  float s = 0.f;
  #pragma unroll
  for (int j=0;j<EE/64;j++) s = fmaf(er[j*64+lane], wr[j*64+lane], s);
  #pragma unroll
  for (int m=1;m<64;m<<=1) s += __shfl_xor(s, m, 64);
  if (lane==0){
    s += b1[h];
    thid[wid] = s/(1.f+expf(-s));
  }
}

__global__ void time_mlp2(const float* __restrict__ thid, const float* __restrict__ w2,
                          const float* __restrict__ b2, float* __restrict__ temb){
  int wid = (blockIdx.x*256 + threadIdx.x)>>6;
  int lane = threadIdx.x & 63;
  int b = wid / EE, e = wid - b*EE;
  const float* tr = thid + b*NH;
  const float* wr = w2 + (size_t)e*NH;
  float s = 0.f;
  #pragma unroll
  for (int j=0;j<NH/64;j++) s = fmaf(tr[j*64+lane], wr[j*64+lane], s);
  #pragma unroll
  for (int m=1;m<64;m<<=1) s += __shfl_xor(s, m, 64);
  if (lane==0) temb[wid] = s + b2[e];
}

__global__ void embed_kernel(const int* __restrict__ tokens, const float* __restrict__ tok_emb,
                             const float* __restrict__ temb, float* __restrict__ x){
  int idx = blockIdx.x*256+threadIdx.x;
  int e = idx % EE; int bl = idx / EE; int b = bl / NL;
  int tok = tokens[bl];
  x[idx] = tok_emb[(size_t)tok*EE + e] + temb[b*EE + e];
}

// ---------------- depthwise causal conv (K=4) + SiLU, bf16 in / fp32 out ----------------
__global__ void conv_silu(const __bf16* __restrict__ xnb, const float* __restrict__ w,
                          float* __restrict__ u){
  int idx = blockIdx.x*256+threadIdx.x;
  int e = idx % EE; int bl = idx / EE; int l = bl % NL;
  float acc = 0.f;
  #pragma unroll
  for (int k=0;k<4;k++){
    int ls = l-3+k;
    if (ls >= 0) acc = fmaf(w[e*4+k], (float)xnb[(size_t)(bl-3+k)*EE + e], acc);
  }
  u[idx] = acc/(1.f+expf(-acc));
}

// ---------------- chunked parallel scan ----------------
__global__ __launch_bounds__(256) void scan_pass1(const float* __restrict__ dt,
    const float* __restrict__ u, const float* __restrict__ A_log,
    float* __restrict__ P, float* __restrict__ S)
{
  int t = blockIdx.x*256 + threadIdx.x;        // B*E*NC threads
  int e = t % EE;
  int cb = t / EE;
  int c = cb & (NC-1), b = cb >> 5;
  float Av[NS], iAv[NS], h[NS], p[NS];
  #pragma unroll
  for (int n4=0;n4<4;n4++){
    float4 v = *(const float4*)(A_log + (size_t)e*NS + n4*4);
    float a0=-expf(v.x), a1=-expf(v.y), a2=-expf(v.z), a3=-expf(v.w);
    Av[n4*4+0]=a0; Av[n4*4+1]=a1; Av[n4*4+2]=a2; Av[n4*4+3]=a3;
    iAv[n4*4+0]=1.f/(a0+1e-10f); iAv[n4*4+1]=1.f/(a1+1e-10f);
    iAv[n4*4+2]=1.f/(a2+1e-10f); iAv[n4*4+3]=1.f/(a3+1e-10f);
  }
  #pragma unroll
  for (int n=0;n<NS;n++){ h[n]=0.f; p[n]=1.f; }
  const int base = c*CL;
  for (int i=0;i<CL;i++){
    int tt = base+i;
    size_t src = (size_t)(b*NL + (tt==0?0:tt-1))*EE + e;
    float dtv = dt[src], uv = u[src];
    if (tt==0){
      #pragma unroll
      for (int n=0;n<NS;n++){
        float at = expf(dtv*Av[n]);
        float bt = (fabsf(Av[n])<1e-5f)? dtv : (at-1.f)*iAv[n];
        h[n] = bt*uv; p[n] = 0.f;
      }
    } else {
      #pragma unroll
      for (int n=0;n<NS;n++){
        float at = expf(dtv*Av[n]);
        float bt = (fabsf(Av[n])<1e-5f)? dtv : (at-1.f)*iAv[n];
        h[n] = fmaf(at, h[n], bt*uv);
        p[n] *= at;
      }
    }
  }
  size_t o = ((size_t)(b*EE + e)*NC + c)*NS;
  #pragma unroll
  for (int n4=0;n4<4;n4++){
    *(float4*)&P[o+n4*4] = make_float4(p[n4*4],p[n4*4+1],p[n4*4+2],p[n4*4+3]);
    *(float4*)&S[o+n4*4] = make_float4(h[n4*4],h[n4*4+1],h[n4*4+2],h[n4*4+3]);
  }
}

__global__ void scan_combine(const float* __restrict__ P, const float* __restrict__ S,
                             float* __restrict__ Hin){
  int t = blockIdx.x*256 + threadIdx.x;   // B*E*NS threads, n fastest
  int n = t & 15; int ec = t >> 4;
  float h = 0.f;
  size_t base = (size_t)ec*NC*NS + n;
  #pragma unroll
  for (int c=0;c<NC;c++){
    Hin[base + c*NS] = h;
    h = P[base + c*NS]*h + S[base + c*NS];
  }
}

__global__ __launch_bounds__(256) void scan_pass2(const float* __restrict__ dt,
    const float* __restrict__ u, const float* __restrict__ zp,
    const float* __restrict__ A_log, const float* __restrict__ Dp,
    const float* __restrict__ Hin, __bf16* __restrict__ gb)
{
  int t = blockIdx.x*256 + threadIdx.x;
  int e = t % EE;
  int cb = t / EE;
  int c = cb & (NC-1), b = cb >> 5;
  float Av[NS], iAv[NS], h[NS];
  #pragma unroll
  for (int n4=0;n4<4;n4++){
    float4 v = *(const float4*)(A_log + (size_t)e*NS + n4*4);
    float a0=-expf(v.x), a1=-expf(v.y), a2=-expf(v.z), a3=-expf(v.w);
    Av[n4*4+0]=a0; Av[n4*4+1]=a1; Av[n4*4+2]=a2; Av[n4*4+3]=a3;
    iAv[n4*4+0]=1.f/(a0+1e-10f); iAv[n4*4+1]=1.f/(a1+1e-10f);
    iAv[n4*4+2]=1.f/(a2+1e-10f); iAv[n4*4+3]=1.f/(a3+1e-10f);
  }
  size_t hb = ((size_t)(b*EE + e)*NC + c)*NS;
  #pragma unroll
  for (int n4=0;n4<4;n4++){
    float4 v = *(const float4*)&Hin[hb+n4*4];
    h[n4*4]=v.x; h[n4*4+1]=v.y; h[n4*4+2]=v.z; h[n4*4+3]=v.w;
  }
  float Dv = Dp[e];
  const int base = c*CL;
  for (int i=0;i<CL;i++){
    int tt = base+i;
    size_t src = (size_t)(b*NL + (tt==0?0:tt-1))*EE + e;
    float dtv = dt[src], uv = u[src];
    if (tt==0){
      #pragma unroll
      for (int n=0;n<NS;n++){
        float at = expf(dtv*Av[n]);
        float bt = (fabsf(Av[n])<1e-5f)? dtv : (at-1.f)*iAv[n];
        h[n] = bt*uv;
      }
    } else {
      #pragma unroll
      for (int n=0;n<NS;n++){
        float at = expf(dtv*Av[n]);
        float bt = (fabsf(Av[n])<1e-5f)? dtv : (at-1.f)*iAv[n];
        h[n] = fmaf(at, h[n], bt*uv);
      }
    }
    const float* cr = zp + (size_t)(b*NL+tt)*ZPW + 832;
    float y = 0.f;
    #pragma unroll
    for (int n4=0;n4<4;n4++){
      float4 cv = *(const float4*)(cr + n4*4);
      y = fmaf(cv.x, h[n4*4], y); y = fmaf(cv.y, h[n4*4+1], y);
      y = fmaf(cv.z, h[n4*4+2], y); y = fmaf(cv.w, h[n4*4+3], y);
    }
    size_t cidx = (size_t)(b*NL+tt)*EE + e;
    float ucur = u[cidx];
    float zv = zp[(size_t)(b*NL+tt)*ZPW + e];
    float sz = zv/(1.f+expf(-zv));
    gb[cidx] = (__bf16)((y + ucur*Dv)*sz);
  }
}

extern "C" void kernel_launch(void* const* d_in, const int* in_sizes, int n_in,
                              void* d_out, int out_size, void* d_ws, size_t ws_size,
                              hipStream_t stream) {
  const int*   tokens    = (const int*)d_in[0];
  const int*   timesteps = (const int*)d_in[1];
  const float* tok_emb   = (const float*)d_in[2];
  const float* time_w1   = (const float*)d_in[3];
  const float* time_b1   = (const float*)d_in[4];
  const float* time_w2   = (const float*)d_in[5];
  const float* time_b2   = (const float*)d_in[6];
  const float* ln1_g     = (const float*)d_in[7];
  const float* ln1_b     = (const float*)d_in[8];
  const float* z_w       = (const float*)d_in[9];
  const float* p_w       = (const float*)d_in[10];
  const float* conv_w    = (const float*)d_in[11];
  const float* dtp_w     = (const float*)d_in[12];
  const float* dtp_b     = (const float*)d_in[13];
  const float* A_log     = (const float*)d_in[14];
  const float* D_param   = (const float*)d_in[15];
  const float* out_w     = (const float*)d_in[16];
  const float* ln2_g     = (const float*)d_in[17];
  const float* ln2_b     = (const float*)d_in[18];
  const float* mlp_w1    = (const float*)d_in[19];
  const float* mlp_b1    = (const float*)d_in[20];
  const float* mlp_w2    = (const float*)d_in[21];
  const float* mlp_b2    = (const float*)d_in[22];
  const float* lnout_g   = (const float*)d_in[23];
  const float* lnout_b   = (const float*)d_in[24];
  const float* head_w    = (const float*)d_in[25];
  const float* head_b    = (const float*)d_in[26];
  float* out = (float*)d_out;

  float* ws = (float*)d_ws;
  float* x      = ws;
  float* zp     = x   + (size_t)M_ROWS*EE;
  float* dt     = zp  + (size_t)M_ROWS*ZPW;
  float* u      = dt  + (size_t)M_ROWS*EE;
  float* P      = u   + (size_t)M_ROWS*EE;
  float* S      = P   + (size_t)NB*EE*NS*NC;
  float* Hin    = S   + (size_t)NB*EE*NS*NC;
  float* emb    = Hin + (size_t)NB*EE*NS*NC;
  float* thid   = emb + NB*EE;
  __bf16* xnb   = (__bf16*)(thid + NB*NH);
  __bf16* gb    = xnb + (size_t)M_ROWS*EE;
  __bf16* hidb  = gb  + (size_t)M_ROWS*EE;
  __bf16* dtunb = hidb + (size_t)M_ROWS*NH;
  __bf16* wzp   = dtunb + (size_t)M_ROWS*128;
  __bf16* wdtp  = wzp  + (size_t)NDEPTH*ZPW*EE;
  __bf16* wout  = wdtp + (size_t)NDEPTH*EE*128;
  __bf16* wm1   = wout + (size_t)NDEPTH*EE*EE;
  __bf16* wm2   = wm1  + (size_t)NDEPTH*NH*EE;
  __bf16* whead = wm2  + (size_t)NDEPTH*EE*NH;

  // ---- weight conversion (5 launches, all layers) ----
  f2b_zp<<<NDEPTH*ZPW*EE/4/256, 256, 0, stream>>>(z_w, p_w, wzp);
  f2b_dtp<<<NDEPTH*EE*128/4/256, 256, 0, stream>>>(dtp_w, wdtp);
  conv_f2b<<<NDEPTH*EE*EE/4/256, 256, 0, stream>>>(out_w, wout, NDEPTH*EE*EE);
  conv_f2b<<<NDEPTH*NH*EE/4/256, 256, 0, stream>>>(mlp_w1, wm1, NDEPTH*NH*EE);
  conv_f2b<<<NDEPTH*EE*NH/4/256, 256, 0, stream>>>(mlp_w2, wm2, NDEPTH*EE*NH);

  sinemb_kernel<<<(NB*EE+255)/256, 256, 0, stream>>>(timesteps, emb);
  time_mlp1<<<NB*NH/4, 256, 0, stream>>>(emb, time_w1, time_b1, thid);
  time_mlp2<<<NB*EE/4, 256, 0, stream>>>(thid, time_w2, time_b2, emb);
  embed_kernel<<<M_ROWS*EE/256, 256, 0, stream>>>(tokens, tok_emb, emb, x);

  const int scan_grid = NB*EE*NC/256;       // 192
  const int comb_grid = NB*EE*NS/256;       // 96

  for (int i=0;i<NDEPTH;i++){
    ln_kernel<<<M_ROWS, 256, 0, stream>>>(x, ln1_g + i*EE, ln1_b + i*EE, xnb);
    gemm_bf16<BE_STORE_ZP,64><<<14*16, 256, 0, stream>>>(
        xnb, wzp + (size_t)i*ZPW*EE, nullptr, zp, dtunb, ZPW, EE, 14, 16);
    gemm_bf16<BE_SOFTPLUS,64><<<12*16, 256, 0, stream>>>(
        dtunb, wdtp + (size_t)i*EE*128, dtp_b + i*EE, dt, nullptr, EE, 128, 12, 16);
    conv_silu<<<M_ROWS*EE/256, 256, 0, stream>>>(xnb, conv_w + (size_t)i*EE*4, u);
    scan_pass1<<<scan_grid, 256, 0, stream>>>(dt, u, A_log + (size_t)i*EE*NS, P, S);
    scan_combine<<<comb_grid, 256, 0, stream>>>(P, S, Hin);
    scan_pass2<<<scan_grid, 256, 0, stream>>>(dt, u, zp,
        A_log + (size_t)i*EE*NS, D_param + i*EE, Hin, gb);
    gemm_bf16<BE_RESID,64><<<12*16, 256, 0, stream>>>(
        gb, wout + (size_t)i*EE*EE, nullptr, x, nullptr, EE, EE, 12, 16);
    ln_kernel<<<M_ROWS, 256, 0, stream>>>(x, ln2_g + i*EE, ln2_b + i*EE, xnb);
    gemm_bf16<BE_BIAS_GELU_B16,128><<<24*16, 256, 0, stream>>>(
        xnb, wm1 + (size_t)i*NH*EE, mlp_b1 + i*NH, hidb, nullptr, NH, EE, 24, 16);
    gemm_bf16<BE_BIAS_RESID,64><<<12*16, 256, 0, stream>>>(
        hidb, wm2 + (size_t)i*EE*NH, mlp_b2 + i*EE, x, nullptr, EE, NH, 12, 16);
  }
  ln_kernel<<<M_ROWS, 256, 0, stream>>>(x, lnout_g, lnout_b, xnb);
  conv_f2b<<<NV*EE/4/256, 256, 0, stream>>>(head_w, whead, NV*EE);
  gemm_bf16<BE_BIAS,128><<<250*16, 256, 0, stream>>>(
      xnb, whead, head_b, out, nullptr, NV, EE, 250, 16);
}

// Round 5
// 1097.565 us; speedup vs baseline: 7.2847x; 1.0466x over previous
//
#include <hip/hip_runtime.h>
#include <math.h>

#define EE 768
#define NS 16
#define RR 48
#define NDEPTH 4
#define NB 2
#define NL 1024
#define NH 3072
#define NV 32000
#define M_ROWS (NB*NL)   // 2048
#define NC 64            // scan chunks
#define CL 16            // chunk length
#define ZPW 896          // z(768) + dt_un(48) + Bu(16) + Cp(16) + pad(48)
#define LOG2E 1.44269504088896f
#define LN2   0.69314718055995f

typedef __attribute__((ext_vector_type(8))) __bf16 bf16x8;
typedef __attribute__((ext_vector_type(4))) __bf16 bf16x4;
typedef __attribute__((ext_vector_type(4))) float f32x4;

__device__ __forceinline__ void gl_lds16(const __bf16* g, __bf16* l){
  __builtin_amdgcn_global_load_lds(
      (const __attribute__((address_space(1))) void*)g,
      (__attribute__((address_space(3))) void*)l, 16, 0, 0);
}

// ---------------- bf16 MFMA GEMM: C = A @ W^T (+epilogues) ----------------
enum { BE_STORE=0, BE_BIAS=1, BE_RESID=2, BE_BIAS_RESID=3, BE_BIAS_GELU_B16=4,
       BE_STORE_ZP=5 };

template<int EPI, int BNT>
__global__ __launch_bounds__(256) void gemm_bf16(const __bf16* __restrict__ A,
    const __bf16* __restrict__ W, const float* __restrict__ bias,
    void* __restrict__ Cv, float* __restrict__ dtf, int N, int K, int gx, int gy)
{
  // bijective XCD swizzle (m204) then GN-grouped ordering for L2 W-reuse
  const int nwg = gx*gy;
  const int orig = blockIdx.x;
  const int q = nwg >> 3, r = nwg & 7;
  const int xcd = orig & 7, bse = orig >> 3;
  int wg = (xcd < r ? xcd*(q+1) : r*(q+1) + (xcd-r)*q) + bse;
  const int GN = 16;
  const int per = gy*GN;
  const int g = wg / per;
  const int gstart = g*GN;
  const int gw0 = gx - gstart;
  const int gw = (GN < gw0) ? GN : gw0;
  const int local = wg - g*per;
  const int bx = gstart + local % gw;
  const int by = local / gw;

  constexpr int NFR = BNT/32;
  __shared__ __bf16 As[128][32];
  __shared__ __bf16 Ws[BNT][32];
  const int bm = by*128, bn = bx*BNT;
  const int tid = threadIdx.x;
  const int w = tid>>6, lane = tid&63;
  const int wr = w>>1, wc = w&1;
  const int fr = lane&15, kg = lane>>4;
  const int srow = lane>>2;
  const int ks = (lane&3) ^ ((srow>>1)&3);   // pre-swizzled source k-slice
  const int sxor = kg ^ ((fr>>1)&3);         // swizzled read slot

  f32x4 acc[4][NFR];
  #pragma unroll
  for (int m=0;m<4;m++)
    #pragma unroll
    for (int n=0;n<NFR;n++)
      acc[m][n] = (f32x4){0.f,0.f,0.f,0.f};

  for (int k0=0;k0<K;k0+=32){
    const __bf16* gA = A + (size_t)(bm + w*32 + srow)*K + k0 + ks*8;
    gl_lds16(gA,                 &As[w*32][0]);
    gl_lds16(gA + (size_t)16*K,  &As[w*32+16][0]);
    if constexpr (BNT==128){
      const __bf16* gW = W + (size_t)(bn + w*32 + srow)*K + k0 + ks*8;
      gl_lds16(gW,                 &Ws[w*32][0]);
      gl_lds16(gW + (size_t)16*K,  &Ws[w*32+16][0]);
    } else {
      const __bf16* gW = W + (size_t)(bn + w*16 + srow)*K + k0 + ks*8;
      gl_lds16(gW, &Ws[w*16][0]);
    }
    __syncthreads();
    bf16x8 af[4], bfr[NFR];
    #pragma unroll
    for (int m=0;m<4;m++) af[m]  = *(const bf16x8*)&As[wr*64 + m*16 + fr][sxor*8];
    #pragma unroll
    for (int n=0;n<NFR;n++) bfr[n] = *(const bf16x8*)&Ws[wc*(BNT/2) + n*16 + fr][sxor*8];
    #pragma unroll
    for (int m=0;m<4;m++)
      #pragma unroll
      for (int n=0;n<NFR;n++)
        acc[m][n] = __builtin_amdgcn_mfma_f32_16x16x32_bf16(af[m], bfr[n], acc[m][n], 0,0,0);
    __syncthreads();
  }

  float* Cf = (float*)Cv;
  __bf16* Cb = (__bf16*)Cv;
  #pragma unroll
  for (int m=0;m<4;m++){
    int row = bm + wr*64 + m*16 + kg*4;
    #pragma unroll
    for (int n=0;n<NFR;n++){
      int col = bn + wc*(BNT/2) + n*16 + fr;
      float bsv = 0.f;
      if (EPI==BE_BIAS || EPI==BE_BIAS_RESID || EPI==BE_BIAS_GELU_B16)
        bsv = bias[col];
      #pragma unroll
      for (int rr2=0;rr2<4;rr2++){
        float v = acc[m][n][rr2];
        size_t idx = (size_t)(row+rr2)*N + col;
        if (EPI==BE_STORE)            Cf[idx] = v;
        else if (EPI==BE_BIAS)        Cf[idx] = v + bsv;
        else if (EPI==BE_RESID)       Cf[idx] += v;
        else if (EPI==BE_BIAS_RESID)  Cf[idx] += v + bsv;
        else if (EPI==BE_BIAS_GELU_B16){
          float xg = v + bsv; Cb[idx] = (__bf16)(0.5f*xg*(1.f+erff(xg*0.70710678118654752f)));
        } else if (EPI==BE_STORE_ZP){
          Cf[idx] = v;
          if (col >= 768 && col < 816) dtf[(size_t)(row+rr2)*RR + (col-768)] = v;
        }
      }
    }
  }
}

// ---------------- weight conversion ----------------
__global__ void conv_f2b(const float* __restrict__ w, __bf16* __restrict__ o, int nelem){
  int i = (blockIdx.x*256 + threadIdx.x)*4;
  if (i >= nelem) return;
  float4 v = *(const float4*)(w+i);
  bf16x4 r = { (__bf16)v.x, (__bf16)v.y, (__bf16)v.z, (__bf16)v.w };
  *(bf16x4*)(o+i) = r;
}

__global__ void f2b_zp(const float* __restrict__ zw, const float* __restrict__ pw,
                       __bf16* __restrict__ o){
  int i4 = blockIdx.x*256 + threadIdx.x;
  const int total = NDEPTH*ZPW*EE/4;
  if (i4 >= total) return;
  int idx = i4*4;
  int layer = idx / (ZPW*EE);
  int rem = idx - layer*(ZPW*EE);
  int row = rem / EE, col = rem - (rem/EE)*EE;
  float4 v;
  if (row < 768)      v = *(const float4*)(zw + ((size_t)layer*EE + row)*EE + col);
  else if (row < 848) v = *(const float4*)(pw + ((size_t)layer*80 + (row-768))*EE + col);
  else                v = make_float4(0.f,0.f,0.f,0.f);
  bf16x4 r = { (__bf16)v.x, (__bf16)v.y, (__bf16)v.z, (__bf16)v.w };
  *(bf16x4*)(o+idx) = r;
}

// ---------------- LayerNorm (row = 768) -> bf16 ----------------
__global__ __launch_bounds__(256) void ln_kernel(const float* __restrict__ x,
    const float* __restrict__ gp, const float* __restrict__ bp, __bf16* __restrict__ yb)
{
  int row = blockIdx.x;
  const float* xr = x + (size_t)row*EE;
  int t = threadIdx.x;
  float v0 = xr[t], v1 = xr[t+256], v2 = xr[t+512];
  float s = v0+v1+v2;
  #pragma unroll
  for (int m=1;m<64;m<<=1) s += __shfl_xor(s, m, 64);
  __shared__ float red[4], red2[4];
  int wid = t>>6;
  if ((t&63)==0) red[wid]=s;
  __syncthreads();
  float mu = (red[0]+red[1]+red[2]+red[3]) * (1.f/768.f);
  float d0=v0-mu, d1=v1-mu, d2=v2-mu;
  float qq = d0*d0+d1*d1+d2*d2;
  #pragma unroll
  for (int m=1;m<64;m<<=1) qq += __shfl_xor(qq, m, 64);
  if ((t&63)==0) red2[wid]=qq;
  __syncthreads();
  float var = (red2[0]+red2[1]+red2[2]+red2[3]) * (1.f/768.f);
  float inv = 1.0f/sqrtf(var + 1e-5f);
  __bf16* ybr = yb + (size_t)row*EE;
  ybr[t]     = (__bf16)(d0*inv*gp[t]     + bp[t]);
  ybr[t+256] = (__bf16)(d1*inv*gp[t+256] + bp[t+256]);
  ybr[t+512] = (__bf16)(d2*inv*gp[t+512] + bp[t+512]);
}

// ---------------- sinusoidal emb + time MLP ----------------
__global__ void sinemb_kernel(const int* __restrict__ timesteps, float* __restrict__ emb){
  int i = blockIdx.x*256+threadIdx.x;
  if (i >= NB*EE) return;
  int b = i/EE, e = i - b*EE;
  int half = EE/2;
  int j = (e<half)? e : e-half;
  float freq = expf(-logf(10000.f)*(float)j/(float)half);
  float arg = (float)timesteps[b]*freq;
  emb[i] = (e<half)? sinf(arg) : cosf(arg);
}

__global__ void time_mlp1(const float* __restrict__ emb, const float* __restrict__ w1,
                          const float* __restrict__ b1, float* __restrict__ thid){
  int wid = (blockIdx.x*256 + threadIdx.x)>>6;
  int lane = threadIdx.x & 63;
  int b = wid / NH, h = wid - b*NH;
  const float* er = emb + b*EE;
  const float* wr = w1 + (size_t)h*EE;
  float s = 0.f;
  #pragma unroll
  for (int j=0;j<EE/64;j++) s = fmaf(er[j*64+lane], wr[j*64+lane], s);
  #pragma unroll
  for (int m=1;m<64;m<<=1) s += __shfl_xor(s, m, 64);
  if (lane==0){
    s += b1[h];
    thid[wid] = s/(1.f+expf(-s));
  }
}

__global__ void time_mlp2(const float* __restrict__ thid, const float* __restrict__ w2,
                          const float* __restrict__ b2, float* __restrict__ temb){
  int wid = (blockIdx.x*256 + threadIdx.x)>>6;
  int lane = threadIdx.x & 63;
  int b = wid / EE, e = wid - b*EE;
  const float* tr = thid + b*NH;
  const float* wr = w2 + (size_t)e*NH;
  float s = 0.f;
  #pragma unroll
  for (int j=0;j<NH/64;j++) s = fmaf(tr[j*64+lane], wr[j*64+lane], s);
  #pragma unroll
  for (int m=1;m<64;m<<=1) s += __shfl_xor(s, m, 64);
  if (lane==0) temb[wid] = s + b2[e];
}

__global__ void embed_kernel(const int* __restrict__ tokens, const float* __restrict__ tok_emb,
                             const float* __restrict__ temb, float* __restrict__ x){
  int idx = blockIdx.x*256+threadIdx.x;
  int e = idx % EE; int bl = idx / EE; int b = bl / NL;
  int tok = tokens[bl];
  x[idx] = tok_emb[(size_t)tok*EE + e] + temb[b*EE + e];
}

// ---------------- fused scan: conv(K=4)+SiLU + dt-proj+softplus in-register ----------------
__device__ __forceinline__ float dot48(const float* __restrict__ row, const float* wdf){
  float a0=0.f,a1=0.f,a2=0.f,a3=0.f;
  #pragma unroll
  for (int j=0;j<12;j++){
    float4 v = *(const float4*)(row + j*4);
    a0 = fmaf(v.x, wdf[j*4+0], a0);
    a1 = fmaf(v.y, wdf[j*4+1], a1);
    a2 = fmaf(v.z, wdf[j*4+2], a2);
    a3 = fmaf(v.w, wdf[j*4+3], a3);
  }
  return (a0+a1)+(a2+a3);
}
__device__ __forceinline__ float softplus_f(float x){
  return fmaxf(x,0.f) + LN2*log2f(1.f + exp2f(-LOG2E*fabsf(x)));
}
__device__ __forceinline__ float silu_f(float x){
  return x/(1.f + exp2f(-LOG2E*x));
}

__global__ __launch_bounds__(256) void scan_pass1(
    const __bf16* __restrict__ xnb, const float* __restrict__ dtun,
    const float* __restrict__ dtw, const float* __restrict__ dtbias,
    const float* __restrict__ cwp, const float* __restrict__ A_log,
    float* __restrict__ P, float* __restrict__ S)
{
  int t = blockIdx.x*256 + threadIdx.x;
  int e = t % EE;
  int cb = t / EE;
  int c = cb & (NC-1), b = cb >> 6;
  float wdf[48];
  #pragma unroll
  for (int j=0;j<12;j++){
    float4 v = *(const float4*)(dtw + (size_t)e*RR + j*4);
    wdf[j*4]=v.x; wdf[j*4+1]=v.y; wdf[j*4+2]=v.z; wdf[j*4+3]=v.w;
  }
  float4 cw = *(const float4*)(cwp + e*4);
  float bias = dtbias[e];
  float Av2[NS], iAv[NS];
  #pragma unroll
  for (int n4=0;n4<4;n4++){
    float4 v = *(const float4*)(A_log + (size_t)e*NS + n4*4);
    float a0=-exp2f(LOG2E*v.x), a1=-exp2f(LOG2E*v.y), a2=-exp2f(LOG2E*v.z), a3=-exp2f(LOG2E*v.w);
    Av2[n4*4+0]=a0*LOG2E; Av2[n4*4+1]=a1*LOG2E; Av2[n4*4+2]=a2*LOG2E; Av2[n4*4+3]=a3*LOG2E;
    iAv[n4*4+0]=1.f/(a0+1e-10f); iAv[n4*4+1]=1.f/(a1+1e-10f);
    iAv[n4*4+2]=1.f/(a2+1e-10f); iAv[n4*4+3]=1.f/(a3+1e-10f);
  }
  const __bf16* xcol = xnb + (size_t)b*NL*EE + e;
  const float* dtrow0 = dtun + (size_t)b*NL*RR;
  const int cs = c*CL;
  float xw0,xw1,xw2,xw3;
  int prow = (c==0)? 0 : cs-1;
  xw0 = (prow-3>=0)? (float)xcol[(size_t)(prow-3)*EE] : 0.f;
  xw1 = (prow-2>=0)? (float)xcol[(size_t)(prow-2)*EE] : 0.f;
  xw2 = (prow-1>=0)? (float)xcol[(size_t)(prow-1)*EE] : 0.f;
  xw3 = (float)xcol[(size_t)prow*EE];
  float up  = silu_f(cw.x*xw0 + cw.y*xw1 + cw.z*xw2 + cw.w*xw3);
  float dtp_ = softplus_f(dot48(dtrow0 + (size_t)prow*RR, wdf) + bias);
  float h[NS], p[NS];
  #pragma unroll
  for (int n=0;n<NS;n++){ h[n]=0.f; p[n]=1.f; }
  for (int i=0;i<CL;i++){
    int tt = cs+i;
    bool z0 = (tt==0);
    #pragma unroll
    for (int n=0;n<NS;n++){
      float at = exp2f(dtp_*Av2[n]);
      float bt = (at-1.f)*iAv[n];
      float s = bt*up;
      h[n] = z0 ? s : fmaf(at, h[n], s);
      p[n] = z0 ? 0.f : p[n]*at;
    }
    if (i<CL-1 && tt>0){
      xw0=xw1; xw1=xw2; xw2=xw3; xw3 = (float)xcol[(size_t)tt*EE];
      up  = silu_f(cw.x*xw0 + cw.y*xw1 + cw.z*xw2 + cw.w*xw3);
      dtp_ = softplus_f(dot48(dtrow0 + (size_t)tt*RR, wdf) + bias);
    }
  }
  size_t o = ((size_t)(b*EE + e)*NC + c)*NS;
  #pragma unroll
  for (int n4=0;n4<4;n4++){
    *(float4*)&P[o+n4*4] = make_float4(p[n4*4],p[n4*4+1],p[n4*4+2],p[n4*4+3]);
    *(float4*)&S[o+n4*4] = make_float4(h[n4*4],h[n4*4+1],h[n4*4+2],h[n4*4+3]);
  }
}

__global__ void scan_combine(const float* __restrict__ P, const float* __restrict__ S,
                             float* __restrict__ Hin){
  int t = blockIdx.x*256 + threadIdx.x;   // B*E*NS threads, n fastest
  int n = t & 15; int ec = t >> 4;
  float h = 0.f;
  size_t base = (size_t)ec*NC*NS + n;
  #pragma unroll
  for (int c=0;c<NC;c++){
    Hin[base + c*NS] = h;
    h = P[base + c*NS]*h + S[base + c*NS];
  }
}

__global__ __launch_bounds__(256) void scan_pass2(
    const __bf16* __restrict__ xnb, const float* __restrict__ dtun,
    const float* __restrict__ dtw, const float* __restrict__ dtbias,
    const float* __restrict__ cwp, const float* __restrict__ A_log,
    const float* __restrict__ Dp, const float* __restrict__ zp,
    const float* __restrict__ Hin, __bf16* __restrict__ gb)
{
  int t = blockIdx.x*256 + threadIdx.x;
  int e = t % EE;
  int cb = t / EE;
  int c = cb & (NC-1), b = cb >> 6;
  float wdf[48];
  #pragma unroll
  for (int j=0;j<12;j++){
    float4 v = *(const float4*)(dtw + (size_t)e*RR + j*4);
    wdf[j*4]=v.x; wdf[j*4+1]=v.y; wdf[j*4+2]=v.z; wdf[j*4+3]=v.w;
  }
  float4 cw = *(const float4*)(cwp + e*4);
  float bias = dtbias[e];
  float Dv = Dp[e];
  float Av2[NS], iAv[NS];
  #pragma unroll
  for (int n4=0;n4<4;n4++){
    float4 v = *(const float4*)(A_log + (size_t)e*NS + n4*4);
    float a0=-exp2f(LOG2E*v.x), a1=-exp2f(LOG2E*v.y), a2=-exp2f(LOG2E*v.z), a3=-exp2f(LOG2E*v.w);
    Av2[n4*4+0]=a0*LOG2E; Av2[n4*4+1]=a1*LOG2E; Av2[n4*4+2]=a2*LOG2E; Av2[n4*4+3]=a3*LOG2E;
    iAv[n4*4+0]=1.f/(a0+1e-10f); iAv[n4*4+1]=1.f/(a1+1e-10f);
    iAv[n4*4+2]=1.f/(a2+1e-10f); iAv[n4*4+3]=1.f/(a3+1e-10f);
  }
  float h[NS];
  size_t hb = ((size_t)(b*EE + e)*NC + c)*NS;
  #pragma unroll
  for (int n4=0;n4<4;n4++){
    float4 v = *(const float4*)&Hin[hb+n4*4];
    h[n4*4]=v.x; h[n4*4+1]=v.y; h[n4*4+2]=v.z; h[n4*4+3]=v.w;
  }
  const __bf16* xcol = xnb + (size_t)b*NL*EE + e;
  const float* dtrow0 = dtun + (size_t)b*NL*RR;
  const int cs = c*CL;
  float xw0,xw1,xw2,xw3;
  int prow = (c==0)? 0 : cs-1;
  xw0 = (prow-3>=0)? (float)xcol[(size_t)(prow-3)*EE] : 0.f;
  xw1 = (prow-2>=0)? (float)xcol[(size_t)(prow-2)*EE] : 0.f;
  xw2 = (prow-1>=0)? (float)xcol[(size_t)(prow-1)*EE] : 0.f;
  xw3 = (float)xcol[(size_t)prow*EE];
  float up  = silu_f(cw.x*xw0 + cw.y*xw1 + cw.z*xw2 + cw.w*xw3);
  float dtp_ = softplus_f(dot48(dtrow0 + (size_t)prow*RR, wdf) + bias);
  for (int i=0;i<CL;i++){
    int tt = cs+i;
    bool z0 = (tt==0);
    #pragma unroll
    for (int n=0;n<NS;n++){
      float at = exp2f(dtp_*Av2[n]);
      float bt = (at-1.f)*iAv[n];
      float s = bt*up;
      h[n] = z0 ? s : fmaf(at, h[n], s);
    }
    float ucur;
    if (tt==0){ ucur = up; }
    else {
      xw0=xw1; xw1=xw2; xw2=xw3; xw3 = (float)xcol[(size_t)tt*EE];
      ucur = silu_f(cw.x*xw0 + cw.y*xw1 + cw.z*xw2 + cw.w*xw3);
    }
    const float* zr = zp + (size_t)(b*NL+tt)*ZPW;
    float y = 0.f;
    #pragma unroll
    for (int n4=0;n4<4;n4++){
      float4 cv = *(const float4*)(zr + 832 + n4*4);
      y = fmaf(cv.x, h[n4*4], y);   y = fmaf(cv.y, h[n4*4+1], y);
      y = fmaf(cv.z, h[n4*4+2], y); y = fmaf(cv.w, h[n4*4+3], y);
    }
    float zv = zr[e];
    gb[(size_t)(b*NL+tt)*EE + e] = (__bf16)((y + ucur*Dv)*silu_f(zv));
    if (i<CL-1 && tt>0){
      dtp_ = softplus_f(dot48(dtrow0 + (size_t)tt*RR, wdf) + bias);
    }
    up = ucur;
  }
}

extern "C" void kernel_launch(void* const* d_in, const int* in_sizes, int n_in,
                              void* d_out, int out_size, void* d_ws, size_t ws_size,
                              hipStream_t stream) {
  const int*   tokens    = (const int*)d_in[0];
  const int*   timesteps = (const int*)d_in[1];
  const float* tok_emb   = (const float*)d_in[2];
  const float* time_w1   = (const float*)d_in[3];
  const float* time_b1   = (const float*)d_in[4];
  const float* time_w2   = (const float*)d_in[5];
  const float* time_b2   = (const float*)d_in[6];
  const float* ln1_g     = (const float*)d_in[7];
  const float* ln1_b     = (const float*)d_in[8];
  const float* z_w       = (const float*)d_in[9];
  const float* p_w       = (const float*)d_in[10];
  const float* conv_w    = (const float*)d_in[11];
  const float* dtp_w     = (const float*)d_in[12];
  const float* dtp_b     = (const float*)d_in[13];
  const float* A_log     = (const float*)d_in[14];
  const float* D_param   = (const float*)d_in[15];
  const float* out_w     = (const float*)d_in[16];
  const float* ln2_g     = (const float*)d_in[17];
  const float* ln2_b     = (const float*)d_in[18];
  const float* mlp_w1    = (const float*)d_in[19];
  const float* mlp_b1    = (const float*)d_in[20];
  const float* mlp_w2    = (const float*)d_in[21];
  const float* mlp_b2    = (const float*)d_in[22];
  const float* lnout_g   = (const float*)d_in[23];
  const float* lnout_b   = (const float*)d_in[24];
  const float* head_w    = (const float*)d_in[25];
  const float* head_b    = (const float*)d_in[26];
  float* out = (float*)d_out;

  float* ws = (float*)d_ws;
  float* x      = ws;
  float* zp     = x    + (size_t)M_ROWS*EE;
  float* dtun   = zp   + (size_t)M_ROWS*ZPW;
  float* P      = dtun + (size_t)M_ROWS*RR;
  float* S      = P    + (size_t)NB*EE*NS*NC;
  float* Hin    = S    + (size_t)NB*EE*NS*NC;
  float* emb    = Hin  + (size_t)NB*EE*NS*NC;
  float* thid   = emb + NB*EE;
  __bf16* xnb   = (__bf16*)(thid + NB*NH);
  __bf16* gb    = xnb + (size_t)M_ROWS*EE;
  __bf16* hidb  = gb  + (size_t)M_ROWS*EE;
  __bf16* wzp   = hidb + (size_t)M_ROWS*NH;
  __bf16* wout  = wzp  + (size_t)NDEPTH*ZPW*EE;
  __bf16* wm1   = wout + (size_t)NDEPTH*EE*EE;
  __bf16* wm2   = wm1  + (size_t)NDEPTH*NH*EE;
  __bf16* whead = wm2  + (size_t)NDEPTH*EE*NH;

  // ---- weight conversion ----
  f2b_zp<<<NDEPTH*ZPW*EE/4/256, 256, 0, stream>>>(z_w, p_w, wzp);
  conv_f2b<<<NDEPTH*EE*EE/4/256, 256, 0, stream>>>(out_w, wout, NDEPTH*EE*EE);
  conv_f2b<<<NDEPTH*NH*EE/4/256, 256, 0, stream>>>(mlp_w1, wm1, NDEPTH*NH*EE);
  conv_f2b<<<NDEPTH*EE*NH/4/256, 256, 0, stream>>>(mlp_w2, wm2, NDEPTH*EE*NH);

  sinemb_kernel<<<(NB*EE+255)/256, 256, 0, stream>>>(timesteps, emb);
  time_mlp1<<<NB*NH/4, 256, 0, stream>>>(emb, time_w1, time_b1, thid);
  time_mlp2<<<NB*EE/4, 256, 0, stream>>>(thid, time_w2, time_b2, emb);
  embed_kernel<<<M_ROWS*EE/256, 256, 0, stream>>>(tokens, tok_emb, emb, x);

  const int scan_grid = NB*EE*NC/256;       // 384
  const int comb_grid = NB*EE*NS/256;       // 96

  for (int i=0;i<NDEPTH;i++){
    const float* dtw = dtp_w + (size_t)i*EE*RR;
    const float* dtb = dtp_b + i*EE;
    const float* cwp = conv_w + (size_t)i*EE*4;
    const float* al  = A_log + (size_t)i*EE*NS;
    ln_kernel<<<M_ROWS, 256, 0, stream>>>(x, ln1_g + i*EE, ln1_b + i*EE, xnb);
    gemm_bf16<BE_STORE_ZP,64><<<14*16, 256, 0, stream>>>(
        xnb, wzp + (size_t)i*ZPW*EE, nullptr, zp, dtun, ZPW, EE, 14, 16);
    scan_pass1<<<scan_grid, 256, 0, stream>>>(xnb, dtun, dtw, dtb, cwp, al, P, S);
    scan_combine<<<comb_grid, 256, 0, stream>>>(P, S, Hin);
    scan_pass2<<<scan_grid, 256, 0, stream>>>(xnb, dtun, dtw, dtb, cwp, al,
        D_param + i*EE, zp, Hin, gb);
    gemm_bf16<BE_RESID,64><<<12*16, 256, 0, stream>>>(
        gb, wout + (size_t)i*EE*EE, nullptr, x, nullptr, EE, EE, 12, 16);
    ln_kernel<<<M_ROWS, 256, 0, stream>>>(x, ln2_g + i*EE, ln2_b + i*EE, xnb);
    gemm_bf16<BE_BIAS_GELU_B16,128><<<24*16, 256, 0, stream>>>(
        xnb, wm1 + (size_t)i*NH*EE, mlp_b1 + i*NH, hidb, nullptr, NH, EE, 24, 16);
    gemm_bf16<BE_BIAS_RESID,64><<<12*16, 256, 0, stream>>>(
        hidb, wm2 + (size_t)i*EE*NH, mlp_b2 + i*EE, x, nullptr, EE, NH, 12, 16);
  }
  ln_kernel<<<M_ROWS, 256, 0, stream>>>(x, lnout_g, lnout_b, xnb);
  conv_f2b<<<NV*EE/4/256, 256, 0, stream>>>(head_w, whead, NV*EE);
  gemm_bf16<BE_BIAS,128><<<250*16, 256, 0, stream>>>(
      xnb, whead, head_b, out, nullptr, NV, EE, 250, 16);
}

// Round 6
// 970.448 us; speedup vs baseline: 8.2389x; 1.1310x over previous
//
#include <hip/hip_runtime.h>
#include <math.h>

#define EE 768
#define NS 16
#define RR 48
#define NDEPTH 4
#define NB 2
#define NL 1024
#define NH 3072
#define NV 32000
#define M_ROWS (NB*NL)   // 2048
#define NC 64            // scan chunks
#define CL 16            // chunk length
#define ZPW 896          // z(768) + dt_un(48) + Bu(16) + Cp(16) + pad(48)
#define LOG2E 1.44269504088896f
#define LN2   0.69314718055995f

typedef __attribute__((ext_vector_type(8))) __bf16 bf16x8;
typedef __attribute__((ext_vector_type(4))) __bf16 bf16x4;
typedef __attribute__((ext_vector_type(4))) float f32x4;

__device__ __forceinline__ void gl_lds16(const __bf16* g, __bf16* l){
  __builtin_amdgcn_global_load_lds(
      (const __attribute__((address_space(1))) void*)g,
      (__attribute__((address_space(3))) void*)l, 16, 0, 0);
}

// ---------------- bf16 MFMA GEMM, BK=64: C = A @ W^T (+epilogues) ----------------
enum { BE_STORE=0, BE_BIAS=1, BE_RESID=2, BE_BIAS_RESID=3, BE_BIAS_GELU_B16=4,
       BE_STORE_ZP=5 };

template<int EPI, int BNT>
__global__ __launch_bounds__(256) void gemm_bf16(const __bf16* __restrict__ A,
    const __bf16* __restrict__ W, const float* __restrict__ bias,
    void* __restrict__ Cv, float* __restrict__ dtf, int N, int K, int gx, int gy)
{
  // bijective XCD swizzle (m204) then GN-grouped ordering for L2 W-reuse
  const int nwg = gx*gy;
  const int orig = blockIdx.x;
  const int q = nwg >> 3, r = nwg & 7;
  const int xcd = orig & 7, bse = orig >> 3;
  int wg = (xcd < r ? xcd*(q+1) : r*(q+1) + (xcd-r)*q) + bse;
  const int GN = 16;
  const int per = gy*GN;
  const int g = wg / per;
  const int gstart = g*GN;
  const int gw0 = gx - gstart;
  const int gw = (GN < gw0) ? GN : gw0;
  const int local = wg - g*per;
  const int bx = gstart + local % gw;
  const int by = local / gw;

  constexpr int NFR = BNT/32;
  __shared__ __bf16 As[128][64];
  __shared__ __bf16 Ws[BNT][64];
  const int bm = by*128, bn = bx*BNT;
  const int tid = threadIdx.x;
  const int w = tid>>6, lane = tid&63;
  const int wr = w>>1, wc = w&1;
  const int fr = lane&15, kg = lane>>4;
  const int sr8 = lane>>3;          // row-in-8-group (0..7)
  const int sg  = lane&7;           // 16B slot (0..7)
  const int ksrc = ((sg ^ sr8) & 7)*8;   // pre-swizzled source k-offset (elems)

  f32x4 acc[4][NFR];
  #pragma unroll
  for (int m=0;m<4;m++)
    #pragma unroll
    for (int n=0;n<NFR;n++)
      acc[m][n] = (f32x4){0.f,0.f,0.f,0.f};

  for (int k0=0;k0<K;k0+=64){
    const __bf16* gA = A + (size_t)(bm + w*32 + sr8)*K + k0 + ksrc;
    #pragma unroll
    for (int c8=0;c8<4;c8++)
      gl_lds16(gA + (size_t)(c8*8)*K, &As[w*32 + c8*8][0]);
    if constexpr (BNT==128){
      const __bf16* gW = W + (size_t)(bn + w*32 + sr8)*K + k0 + ksrc;
      #pragma unroll
      for (int c8=0;c8<4;c8++)
        gl_lds16(gW + (size_t)(c8*8)*K, &Ws[w*32 + c8*8][0]);
    } else {
      const __bf16* gW = W + (size_t)(bn + w*16 + sr8)*K + k0 + ksrc;
      #pragma unroll
      for (int c8=0;c8<2;c8++)
        gl_lds16(gW + (size_t)(c8*8)*K, &Ws[w*16 + c8*8][0]);
    }
    __syncthreads();
    #pragma unroll
    for (int kk=0;kk<2;kk++){
      const int sp = (((kg + kk*4) ^ (fr&7)) & 7) * 8;
      bf16x8 af[4], bfr[NFR];
      #pragma unroll
      for (int m=0;m<4;m++) af[m]  = *(const bf16x8*)&As[wr*64 + m*16 + fr][sp];
      #pragma unroll
      for (int n=0;n<NFR;n++) bfr[n] = *(const bf16x8*)&Ws[wc*(BNT/2) + n*16 + fr][sp];
      #pragma unroll
      for (int m=0;m<4;m++)
        #pragma unroll
        for (int n=0;n<NFR;n++)
          acc[m][n] = __builtin_amdgcn_mfma_f32_16x16x32_bf16(af[m], bfr[n], acc[m][n], 0,0,0);
    }
    __syncthreads();
  }

  float* Cf = (float*)Cv;
  __bf16* Cb = (__bf16*)Cv;
  #pragma unroll
  for (int m=0;m<4;m++){
    int row = bm + wr*64 + m*16 + kg*4;
    #pragma unroll
    for (int n=0;n<NFR;n++){
      int col = bn + wc*(BNT/2) + n*16 + fr;
      float bsv = 0.f;
      if (EPI==BE_BIAS || EPI==BE_BIAS_RESID || EPI==BE_BIAS_GELU_B16)
        bsv = bias[col];
      #pragma unroll
      for (int rr2=0;rr2<4;rr2++){
        float v = acc[m][n][rr2];
        size_t idx = (size_t)(row+rr2)*N + col;
        if (EPI==BE_STORE)            Cf[idx] = v;
        else if (EPI==BE_BIAS)        Cf[idx] = v + bsv;
        else if (EPI==BE_RESID)       Cf[idx] += v;
        else if (EPI==BE_BIAS_RESID)  Cf[idx] += v + bsv;
        else if (EPI==BE_BIAS_GELU_B16){
          float xg = v + bsv; Cb[idx] = (__bf16)(0.5f*xg*(1.f+erff(xg*0.70710678118654752f)));
        } else if (EPI==BE_STORE_ZP){
          Cf[idx] = v;
          if (col >= 768 && col < 816) dtf[(size_t)(row+rr2)*RR + (col-768)] = v;
        }
      }
    }
  }
}

// ---------------- merged weight conversion (ALL weights, one dispatch) ----------------
#define S1E 2752512LL    // wzp  : 4*896*768
#define S2E 5111808LL    // wout : +4*768*768
#define S3E 14548992LL   // wm1  : +4*3072*768
#define S4E 23986176LL   // wm2  : +4*768*3072
#define STOT 48562176LL  // whead: +32000*768

__global__ void f2b_all(const float* __restrict__ zw, const float* __restrict__ pw,
                        const float* __restrict__ ow, const float* __restrict__ m1,
                        const float* __restrict__ m2, const float* __restrict__ hw,
                        __bf16* __restrict__ o){
  long long idx = ((long long)blockIdx.x*256 + threadIdx.x)*4;
  if (idx >= STOT) return;
  float4 v;
  if (idx < S1E){
    long long layer = idx / (ZPW*EE);
    int rem = (int)(idx - layer*(ZPW*EE));
    int row = rem / EE, col = rem - (rem/EE)*EE;
    if (row < 768)      v = *(const float4*)(zw + ((size_t)layer*EE + row)*EE + col);
    else if (row < 848) v = *(const float4*)(pw + ((size_t)layer*80 + (row-768))*EE + col);
    else                v = make_float4(0.f,0.f,0.f,0.f);
  }
  else if (idx < S2E) v = *(const float4*)(ow + (idx - S1E));
  else if (idx < S3E) v = *(const float4*)(m1 + (idx - S2E));
  else if (idx < S4E) v = *(const float4*)(m2 + (idx - S3E));
  else                v = *(const float4*)(hw + (idx - S4E));
  bf16x4 rb = { (__bf16)v.x, (__bf16)v.y, (__bf16)v.z, (__bf16)v.w };
  *(bf16x4*)(o+idx) = rb;
}

// ---------------- LayerNorm (row = 768) -> bf16 ----------------
__global__ __launch_bounds__(256) void ln_kernel(const float* __restrict__ x,
    const float* __restrict__ gp, const float* __restrict__ bp, __bf16* __restrict__ yb)
{
  int row = blockIdx.x;
  const float* xr = x + (size_t)row*EE;
  int t = threadIdx.x;
  float v0 = xr[t], v1 = xr[t+256], v2 = xr[t+512];
  float s = v0+v1+v2;
  #pragma unroll
  for (int m=1;m<64;m<<=1) s += __shfl_xor(s, m, 64);
  __shared__ float red[4], red2[4];
  int wid = t>>6;
  if ((t&63)==0) red[wid]=s;
  __syncthreads();
  float mu = (red[0]+red[1]+red[2]+red[3]) * (1.f/768.f);
  float d0=v0-mu, d1=v1-mu, d2=v2-mu;
  float qq = d0*d0+d1*d1+d2*d2;
  #pragma unroll
  for (int m=1;m<64;m<<=1) qq += __shfl_xor(qq, m, 64);
  if ((t&63)==0) red2[wid]=qq;
  __syncthreads();
  float var = (red2[0]+red2[1]+red2[2]+red2[3]) * (1.f/768.f);
  float inv = 1.0f/sqrtf(var + 1e-5f);
  __bf16* ybr = yb + (size_t)row*EE;
  ybr[t]     = (__bf16)(d0*inv*gp[t]     + bp[t]);
  ybr[t+256] = (__bf16)(d1*inv*gp[t+256] + bp[t+256]);
  ybr[t+512] = (__bf16)(d2*inv*gp[t+512] + bp[t+512]);
}

// ---------------- sinusoidal emb + time MLP ----------------
__global__ void sinemb_kernel(const int* __restrict__ timesteps, float* __restrict__ emb){
  int i = blockIdx.x*256+threadIdx.x;
  if (i >= NB*EE) return;
  int b = i/EE, e = i - b*EE;
  int half = EE/2;
  int j = (e<half)? e : e-half;
  float freq = expf(-logf(10000.f)*(float)j/(float)half);
  float arg = (float)timesteps[b]*freq;
  emb[i] = (e<half)? sinf(arg) : cosf(arg);
}

__global__ void time_mlp1(const float* __restrict__ emb, const float* __restrict__ w1,
                          const float* __restrict__ b1, float* __restrict__ thid){
  int wid = (blockIdx.x*256 + threadIdx.x)>>6;
  int lane = threadIdx.x & 63;
  int b = wid / NH, h = wid - b*NH;
  const float* er = emb + b*EE;
  const float* wr = w1 + (size_t)h*EE;
  float s = 0.f;
  #pragma unroll
  for (int j=0;j<EE/64;j++) s = fmaf(er[j*64+lane], wr[j*64+lane], s);
  #pragma unroll
  for (int m=1;m<64;m<<=1) s += __shfl_xor(s, m, 64);
  if (lane==0){
    s += b1[h];
    thid[wid] = s/(1.f+expf(-s));
  }
}

__global__ void time_mlp2(const float* __restrict__ thid, const float* __restrict__ w2,
                          const float* __restrict__ b2, float* __restrict__ temb){
  int wid = (blockIdx.x*256 + threadIdx.x)>>6;
  int lane = threadIdx.x & 63;
  int b = wid / EE, e = wid - b*EE;
  const float* tr = thid + b*NH;
  const float* wr = w2 + (size_t)e*NH;
  float s = 0.f;
  #pragma unroll
  for (int j=0;j<NH/64;j++) s = fmaf(tr[j*64+lane], wr[j*64+lane], s);
  #pragma unroll
  for (int m=1;m<64;m<<=1) s += __shfl_xor(s, m, 64);
  if (lane==0) temb[wid] = s + b2[e];
}

__global__ void embed_kernel(const int* __restrict__ tokens, const float* __restrict__ tok_emb,
                             const float* __restrict__ temb, float* __restrict__ x){
  int idx = blockIdx.x*256+threadIdx.x;
  int e = idx % EE; int bl = idx / EE; int b = bl / NL;
  int tok = tokens[bl];
  x[idx] = tok_emb[(size_t)tok*EE + e] + temb[b*EE + e];
}

// ---------------- fully fused scan (conv+SiLU + dt-proj+softplus + 3-phase scan) ----------------
__device__ __forceinline__ float dot48(const float* __restrict__ row, const float* wdf){
  float a0=0.f,a1=0.f,a2=0.f,a3=0.f;
  #pragma unroll
  for (int j=0;j<12;j++){
    float4 v = *(const float4*)(row + j*4);
    a0 = fmaf(v.x, wdf[j*4+0], a0);
    a1 = fmaf(v.y, wdf[j*4+1], a1);
    a2 = fmaf(v.z, wdf[j*4+2], a2);
    a3 = fmaf(v.w, wdf[j*4+3], a3);
  }
  return (a0+a1)+(a2+a3);
}
__device__ __forceinline__ float softplus_f(float x){
  return fmaxf(x,0.f) + LN2*log2f(1.f + exp2f(-LOG2E*fabsf(x)));
}
__device__ __forceinline__ float silu_f(float x){
  return x/(1.f + exp2f(-LOG2E*x));
}

// block = (b, 8 e-columns); threads = 8 e x 64 chunks; chain length 1024 = 64*16
__global__ __launch_bounds__(512) void scan_fused(
    const __bf16* __restrict__ xnb, const float* __restrict__ dtun,
    const float* __restrict__ dtw, const float* __restrict__ dtbias,
    const float* __restrict__ cwp, const float* __restrict__ A_log,
    const float* __restrict__ Dp, const float* __restrict__ zp,
    __bf16* __restrict__ gb)
{
  __shared__ float Pl[NC][8][NS];
  __shared__ float Sl[NC][8][NS];
  const int tid = threadIdx.x;
  const int e_l = tid & 7, c = tid >> 3;        // c in 0..63
  const int b  = blockIdx.x / (EE/8);
  const int eg = blockIdx.x % (EE/8);
  const int e  = eg*8 + e_l;

  float wdf[48];
  #pragma unroll
  for (int j=0;j<12;j++){
    float4 v = *(const float4*)(dtw + (size_t)e*RR + j*4);
    wdf[j*4]=v.x; wdf[j*4+1]=v.y; wdf[j*4+2]=v.z; wdf[j*4+3]=v.w;
  }
  float4 cw = *(const float4*)(cwp + e*4);
  float bias = dtbias[e];
  float Dv = Dp[e];
  float Av2[NS], iAv[NS];
  #pragma unroll
  for (int n4=0;n4<4;n4++){
    float4 v = *(const float4*)(A_log + (size_t)e*NS + n4*4);
    float a0=-exp2f(LOG2E*v.x), a1=-exp2f(LOG2E*v.y), a2=-exp2f(LOG2E*v.z), a3=-exp2f(LOG2E*v.w);
    Av2[n4*4+0]=a0*LOG2E; Av2[n4*4+1]=a1*LOG2E; Av2[n4*4+2]=a2*LOG2E; Av2[n4*4+3]=a3*LOG2E;
    iAv[n4*4+0]=1.f/(a0+1e-10f); iAv[n4*4+1]=1.f/(a1+1e-10f);
    iAv[n4*4+2]=1.f/(a2+1e-10f); iAv[n4*4+3]=1.f/(a3+1e-10f);
  }
  const __bf16* xcol = xnb + (size_t)b*NL*EE + e;
  const float* dtrow0 = dtun + (size_t)b*NL*RR;
  const int cs = c*CL;

  // ---- phase 1: per-chunk (p, h) ----
  {
    float xw0,xw1,xw2,xw3;
    int prow = (c==0)? 0 : cs-1;
    xw0 = (prow-3>=0)? (float)xcol[(size_t)(prow-3)*EE] : 0.f;
    xw1 = (prow-2>=0)? (float)xcol[(size_t)(prow-2)*EE] : 0.f;
    xw2 = (prow-1>=0)? (float)xcol[(size_t)(prow-1)*EE] : 0.f;
    xw3 = (float)xcol[(size_t)prow*EE];
    float up  = silu_f(cw.x*xw0 + cw.y*xw1 + cw.z*xw2 + cw.w*xw3);
    float dtp_ = softplus_f(dot48(dtrow0 + (size_t)prow*RR, wdf) + bias);
    float h[NS], p[NS];
    #pragma unroll
    for (int n=0;n<NS;n++){ h[n]=0.f; p[n]=1.f; }
    for (int i=0;i<CL;i++){
      int tt = cs+i;
      bool z0 = (tt==0);
      #pragma unroll
      for (int n=0;n<NS;n++){
        float at = exp2f(dtp_*Av2[n]);
        float bt = (at-1.f)*iAv[n];
        float s = bt*up;
        h[n] = z0 ? s : fmaf(at, h[n], s);
        p[n] = z0 ? 0.f : p[n]*at;
      }
      if (i<CL-1 && tt>0){
        xw0=xw1; xw1=xw2; xw2=xw3; xw3 = (float)xcol[(size_t)tt*EE];
        up  = silu_f(cw.x*xw0 + cw.y*xw1 + cw.z*xw2 + cw.w*xw3);
        dtp_ = softplus_f(dot48(dtrow0 + (size_t)tt*RR, wdf) + bias);
      }
    }
    #pragma unroll
    for (int n4=0;n4<4;n4++){
      *(float4*)&Pl[c][e_l][n4*4] = make_float4(p[n4*4],p[n4*4+1],p[n4*4+2],p[n4*4+3]);
      *(float4*)&Sl[c][e_l][n4*4] = make_float4(h[n4*4],h[n4*4+1],h[n4*4+2],h[n4*4+3]);
    }
  }
  __syncthreads();
  // ---- phase 2: in-LDS combine across chunks (Hin overwrites Pl) ----
  if (tid < 128){
    int el2 = tid & 7, n = tid >> 3;
    float hh = 0.f;
    for (int cc=0; cc<NC; cc++){
      float pp = Pl[cc][el2][n], ss = Sl[cc][el2][n];
      Pl[cc][el2][n] = hh;
      hh = fmaf(pp, hh, ss);
    }
  }
  __syncthreads();
  // ---- phase 3: re-walk chunk with correct initial state, emit g ----
  {
    float h[NS];
    #pragma unroll
    for (int n4=0;n4<4;n4++){
      float4 v = *(const float4*)&Pl[c][e_l][n4*4];
      h[n4*4]=v.x; h[n4*4+1]=v.y; h[n4*4+2]=v.z; h[n4*4+3]=v.w;
    }
    float xw0,xw1,xw2,xw3;
    int prow = (c==0)? 0 : cs-1;
    xw0 = (prow-3>=0)? (float)xcol[(size_t)(prow-3)*EE] : 0.f;
    xw1 = (prow-2>=0)? (float)xcol[(size_t)(prow-2)*EE] : 0.f;
    xw2 = (prow-1>=0)? (float)xcol[(size_t)(prow-1)*EE] : 0.f;
    xw3 = (float)xcol[(size_t)prow*EE];
    float up  = silu_f(cw.x*xw0 + cw.y*xw1 + cw.z*xw2 + cw.w*xw3);
    float dtp_ = softplus_f(dot48(dtrow0 + (size_t)prow*RR, wdf) + bias);
    for (int i=0;i<CL;i++){
      int tt = cs+i;
      bool z0 = (tt==0);
      #pragma unroll
      for (int n=0;n<NS;n++){
        float at = exp2f(dtp_*Av2[n]);
        float bt = (at-1.f)*iAv[n];
        float s = bt*up;
        h[n] = z0 ? s : fmaf(at, h[n], s);
      }
      float ucur;
      if (tt==0){ ucur = up; }
      else {
        xw0=xw1; xw1=xw2; xw2=xw3; xw3 = (float)xcol[(size_t)tt*EE];
        ucur = silu_f(cw.x*xw0 + cw.y*xw1 + cw.z*xw2 + cw.w*xw3);
      }
      const float* zr = zp + (size_t)(b*NL+tt)*ZPW;
      float y = 0.f;
      #pragma unroll
      for (int n4=0;n4<4;n4++){
        float4 cv = *(const float4*)(zr + 832 + n4*4);
        y = fmaf(cv.x, h[n4*4], y);   y = fmaf(cv.y, h[n4*4+1], y);
        y = fmaf(cv.z, h[n4*4+2], y); y = fmaf(cv.w, h[n4*4+3], y);
      }
      float zv = zr[e];
      gb[(size_t)(b*NL+tt)*EE + e] = (__bf16)((y + ucur*Dv)*silu_f(zv));
      if (i<CL-1 && tt>0){
        dtp_ = softplus_f(dot48(dtrow0 + (size_t)tt*RR, wdf) + bias);
      }
      up = ucur;
    }
  }
}

extern "C" void kernel_launch(void* const* d_in, const int* in_sizes, int n_in,
                              void* d_out, int out_size, void* d_ws, size_t ws_size,
                              hipStream_t stream) {
  const int*   tokens    = (const int*)d_in[0];
  const int*   timesteps = (const int*)d_in[1];
  const float* tok_emb   = (const float*)d_in[2];
  const float* time_w1   = (const float*)d_in[3];
  const float* time_b1   = (const float*)d_in[4];
  const float* time_w2   = (const float*)d_in[5];
  const float* time_b2   = (const float*)d_in[6];
  const float* ln1_g     = (const float*)d_in[7];
  const float* ln1_b     = (const float*)d_in[8];
  const float* z_w       = (const float*)d_in[9];
  const float* p_w       = (const float*)d_in[10];
  const float* conv_w    = (const float*)d_in[11];
  const float* dtp_w     = (const float*)d_in[12];
  const float* dtp_b     = (const float*)d_in[13];
  const float* A_log     = (const float*)d_in[14];
  const float* D_param   = (const float*)d_in[15];
  const float* out_w     = (const float*)d_in[16];
  const float* ln2_g     = (const float*)d_in[17];
  const float* ln2_b     = (const float*)d_in[18];
  const float* mlp_w1    = (const float*)d_in[19];
  const float* mlp_b1    = (const float*)d_in[20];
  const float* mlp_w2    = (const float*)d_in[21];
  const float* mlp_b2    = (const float*)d_in[22];
  const float* lnout_g   = (const float*)d_in[23];
  const float* lnout_b   = (const float*)d_in[24];
  const float* head_w    = (const float*)d_in[25];
  const float* head_b    = (const float*)d_in[26];
  float* out = (float*)d_out;

  float* ws = (float*)d_ws;
  float* x      = ws;
  float* zp     = x    + (size_t)M_ROWS*EE;
  float* dtun   = zp   + (size_t)M_ROWS*ZPW;
  float* emb    = dtun + (size_t)M_ROWS*RR;
  float* thid   = emb + NB*EE;
  __bf16* xnb   = (__bf16*)(thid + NB*NH);
  __bf16* gb    = xnb + (size_t)M_ROWS*EE;
  __bf16* hidb  = gb  + (size_t)M_ROWS*EE;
  __bf16* wzp   = hidb + (size_t)M_ROWS*NH;
  __bf16* wout  = wzp  + (size_t)NDEPTH*ZPW*EE;
  __bf16* wm1   = wout + (size_t)NDEPTH*EE*EE;
  __bf16* wm2   = wm1  + (size_t)NDEPTH*NH*EE;
  __bf16* whead = wm2  + (size_t)NDEPTH*EE*NH;

  // ---- all weight conversions in ONE dispatch (contiguous dest = wzp..whead) ----
  f2b_all<<<(int)(STOT/4/256), 256, 0, stream>>>(z_w, p_w, out_w, mlp_w1, mlp_w2, head_w, wzp);

  sinemb_kernel<<<(NB*EE+255)/256, 256, 0, stream>>>(timesteps, emb);
  time_mlp1<<<NB*NH/4, 256, 0, stream>>>(emb, time_w1, time_b1, thid);
  time_mlp2<<<NB*EE/4, 256, 0, stream>>>(thid, time_w2, time_b2, emb);
  embed_kernel<<<M_ROWS*EE/256, 256, 0, stream>>>(tokens, tok_emb, emb, x);

  const int scan_grid = NB*EE/8;            // 192 blocks x 512 threads

  for (int i=0;i<NDEPTH;i++){
    const float* dtw = dtp_w + (size_t)i*EE*RR;
    const float* dtb = dtp_b + i*EE;
    const float* cwp = conv_w + (size_t)i*EE*4;
    const float* al  = A_log + (size_t)i*EE*NS;
    ln_kernel<<<M_ROWS, 256, 0, stream>>>(x, ln1_g + i*EE, ln1_b + i*EE, xnb);
    gemm_bf16<BE_STORE_ZP,64><<<14*16, 256, 0, stream>>>(
        xnb, wzp + (size_t)i*ZPW*EE, nullptr, zp, dtun, ZPW, EE, 14, 16);
    scan_fused<<<scan_grid, 512, 0, stream>>>(xnb, dtun, dtw, dtb, cwp, al,
        D_param + i*EE, zp, gb);
    gemm_bf16<BE_RESID,64><<<12*16, 256, 0, stream>>>(
        gb, wout + (size_t)i*EE*EE, nullptr, x, nullptr, EE, EE, 12, 16);
    ln_kernel<<<M_ROWS, 256, 0, stream>>>(x, ln2_g + i*EE, ln2_b + i*EE, xnb);
    gemm_bf16<BE_BIAS_GELU_B16,128><<<24*16, 256, 0, stream>>>(
        xnb, wm1 + (size_t)i*NH*EE, mlp_b1 + i*NH, hidb, nullptr, NH, EE, 24, 16);
    gemm_bf16<BE_BIAS_RESID,64><<<12*16, 256, 0, stream>>>(
        hidb, wm2 + (size_t)i*EE*NH, mlp_b2 + i*EE, x, nullptr, EE, NH, 12, 16);
  }
  ln_kernel<<<M_ROWS, 256, 0, stream>>>(x, lnout_g, lnout_b, xnb);
  gemm_bf16<BE_BIAS,128><<<250*16, 256, 0, stream>>>(
      xnb, whead, head_b, out, nullptr, NV, EE, 250, 16);
}